// Round 11
// baseline (607.465 us; speedup 1.0000x reference)
//
#include <hip/hip_runtime.h>
#include <hip/hip_bf16.h>

typedef __bf16 bf16_t;
typedef bf16_t bf16x8 __attribute__((ext_vector_type(8)));
typedef float f32x4 __attribute__((ext_vector_type(4)));

// Pyramid layout: P[hg][16352][64] bf16, hg = b*16+h (64 head-groups).
// Row offsets per level l: {0,8192,12288,14336,15360,15872,16128,16256,16320}.
// Levels 1-3 are NEVER materialized (derived on the fly in attn_comb).
#define PROWS 16352

// ---------------------------------------------------------------- helpers
__device__ __forceinline__ void gl_lds16(const bf16_t* g, bf16_t* l) {
  __builtin_amdgcn_global_load_lds(
      (const __attribute__((address_space(1))) void*)g,
      (__attribute__((address_space(3))) void*)l,
      16, 0, 0);
}

__device__ __forceinline__ void load8f(const bf16_t* p, float* f) {
  bf16x8 v = *(const bf16x8*)p;
#pragma unroll
  for (int e = 0; e < 8; ++e) f[e] = (float)v[e];
}
__device__ __forceinline__ void store8f(bf16_t* p, const float* f) {
  bf16x8 v;
#pragma unroll
  for (int e = 0; e < 8; ++e) v[e] = (bf16_t)f[e];
  *(bf16x8*)p = v;
}

// ---------------------------------------------------------------- fp32 -> bf16 (x)
__global__ __launch_bounds__(256) void cvt_f32_to_bf16(const float* __restrict__ in,
                                                       bf16_t* __restrict__ o) {
  size_t gid = (size_t)blockIdx.x * 256 + threadIdx.x;
  const float4* p = (const float4*)in + gid * 2;
  float4 a = p[0], b = p[1];
  bf16x8 v;
  v[0] = (bf16_t)a.x; v[1] = (bf16_t)a.y; v[2] = (bf16_t)a.z; v[3] = (bf16_t)a.w;
  v[4] = (bf16_t)b.x; v[5] = (bf16_t)b.y; v[6] = (bf16_t)b.z; v[7] = (bf16_t)b.w;
  *(bf16x8*)(o + gid * 8) = v;
}

// ---------------------------------------------------------------- weight transpose + cast: w[K][N] -> wT[N][K] bf16
__global__ __launch_bounds__(256) void transpose_to_bf16(const float* __restrict__ w,
                                                         bf16_t* __restrict__ wT,
                                                         int K, int N) {
  __shared__ float t[32][33];
  int bx = blockIdx.x, by = blockIdx.y;
  int tx = threadIdx.x & 31, ty = threadIdx.x >> 5;
#pragma unroll
  for (int r = ty; r < 32; r += 8)
    t[r][tx] = w[(size_t)(by * 32 + r) * N + bx * 32 + tx];
  __syncthreads();
#pragma unroll
  for (int r = ty; r < 32; r += 8)
    wT[(size_t)(bx * 32 + r) * K + by * 32 + tx] = (bf16_t)t[tx][r];
}

// ---------------------------------------------------------------- 128x128 dbuf GEMM, 2 blocks/CU (TLP schedule)
// C[M][N] = A[M][K=1024] @ Bt[N][K=1024]^T.  4 waves (256 thr), BK=64,
// double-buffered LDS 64 KiB -> TWO blocks co-resident per CU: one block's
// stage/vmcnt/barrier stalls overlap the other's MFMA (m114 mechanism).
// Per K-step: stage t+1 -> buf^1 (8 gload_lds/wave), counted vmcnt(8)
// (waits only tile t, issued one step ago -> HBM latency hidden), barrier,
// 16 ds_read_b128 (T2-swizzled) + 32 MFMA, lgkmcnt(0), barrier.
// T2 swizzle: k-slot' = k-slot ^ (row&7); linear gl_lds dest + pre-swizzled
// global source + swizzled ds_read (rule #21). Conflict-free (2-way max).
// EPI 0: scatter bf16 into pyramid P (qkv de-interleave, q scaled 0.125).
// EPI 1: fp32 C + bias.
template <int EPI>
__global__ __launch_bounds__(256) void gemm128d(const bf16_t* __restrict__ A,
                                                const bf16_t* __restrict__ Bt,
                                                float* __restrict__ Cp,
                                                const float* __restrict__ bias,
                                                bf16_t* __restrict__ Pq,
                                                bf16_t* __restrict__ Pk,
                                                bf16_t* __restrict__ Pv,
                                                int ldc, int nTilesN) {
  __shared__ __align__(16) bf16_t As[2 * 128 * 64];   // 2 x 16 KiB
  __shared__ __align__(16) bf16_t Bs[2 * 128 * 64];
  const int tid = threadIdx.x;
  const int w = tid >> 6, lane = tid & 63;

  // XCD-chunked, ntile-fast decode (adjacent blocks share the A row-panel)
  const int nwg = gridDim.x;                      // multiple of 8
  const int chunk = (blockIdx.x & 7) * (nwg >> 3) + (blockIdx.x >> 3);
  const int mt = chunk / nTilesN, ntile = chunk % nTilesN;
  const int bm = mt * 128, bn = ntile * 128;

  const int wr = w >> 1, wc = w & 1;              // 2x2 wave grid; wave tile 64x64
  const int lr = lane & 15, lg = lane >> 4;
  const int sw = lr & 7;                          // T2 read-side XOR key
  f32x4 acc[4][4] = {};

  // stage one full 128x64 matrix: 16 x 1KB chunk-blocks, 4 per wave
  auto stageMat = [&](const bf16_t* __restrict__ G, int rbase, int kt,
                      bf16_t* lbuf) {
#pragma unroll
    for (int j = 0; j < 4; ++j) {
      int b = j * 4 + w;
      int r3 = lane >> 3;                          // row & 7
      int k8 = (lane & 7) ^ r3;                    // T2 pre-swizzled source slot
      gl_lds16(G + (size_t)(rbase + b * 8 + r3) * 1024 + kt + k8 * 8,
               lbuf + b * 512);
    }
  };

  // prologue: tile 0 -> buf0 (8 gloads/wave outstanding)
  stageMat(A, bm, 0, As);
  stageMat(Bt, bn, 0, Bs);

  for (int t = 0; t < 16; ++t) {
    const int c = t & 1;
    bf16_t* Ac = As + c * 8192;
    bf16_t* Bc = Bs + c * 8192;
    if (t < 15) {
      const int kt1 = (t + 1) << 6;
      stageMat(A, bm, kt1, As + (c ^ 1) * 8192);   // outstanding: 16
      stageMat(Bt, bn, kt1, Bs + (c ^ 1) * 8192);
      asm volatile("s_waitcnt vmcnt(8)" ::: "memory");   // tile t landed
    } else {
      asm volatile("s_waitcnt vmcnt(0)" ::: "memory");   // tail drain
    }
    __builtin_amdgcn_s_barrier();                  // publish tile t to all waves

    bf16x8 af[4][2], bfv[4][2];
#pragma unroll
    for (int fi = 0; fi < 4; ++fi)
#pragma unroll
      for (int kk = 0; kk < 2; ++kk)
        af[fi][kk] = *(const bf16x8*)&Ac[(wr * 64 + fi * 16 + lr) * 64 +
                                         (((kk * 4 + lg) ^ sw) * 8)];
#pragma unroll
    for (int fj = 0; fj < 4; ++fj)
#pragma unroll
      for (int kk = 0; kk < 2; ++kk)
        bfv[fj][kk] = *(const bf16x8*)&Bc[(wc * 64 + fj * 16 + lr) * 64 +
                                          (((kk * 4 + lg) ^ sw) * 8)];
#pragma unroll
    for (int kk = 0; kk < 2; ++kk)
#pragma unroll
      for (int fi = 0; fi < 4; ++fi)
#pragma unroll
        for (int fj = 0; fj < 4; ++fj)
          acc[fi][fj] = __builtin_amdgcn_mfma_f32_16x16x32_bf16(
              af[fi][kk], bfv[fj][kk], acc[fi][fj], 0, 0, 0);

    asm volatile("s_waitcnt lgkmcnt(0)" ::: "memory");   // my reads of buf[c] retired
    __builtin_amdgcn_sched_barrier(0);
    __builtin_amdgcn_s_barrier();                  // buf[c] free for stage at t+1
  }

  // ---- epilogue
  if (EPI == 1) {
    float bv[4];
#pragma unroll
    for (int fj = 0; fj < 4; ++fj) bv[fj] = bias[bn + wc * 64 + fj * 16 + lr];
#pragma unroll
    for (int fi = 0; fi < 4; ++fi)
#pragma unroll
      for (int fj = 0; fj < 4; ++fj)
#pragma unroll
        for (int r = 0; r < 4; ++r) {
          int row = bm + wr * 64 + fi * 16 + lg * 4 + r;
          int col = bn + wc * 64 + fj * 16 + lr;
          Cp[(size_t)row * ldc + col] = acc[fi][fj][r] + bv[fj];
        }
  } else {
    // hoisted scatter: per-fj base pointer; 128-aligned tiles never straddle
    // the 8192-row boundary -> hg/trow base are per-tile constants.
    const int trow0 = (bm & 8191) + wr * 64 + lg * 4;
    const int hgRow = (bm >> 13) << 4;
#pragma unroll
    for (int fj = 0; fj < 4; ++fj) {
      int col = bn + wc * 64 + fj * 16 + lr;
      int tns = col >> 10, col10 = col & 1023;
      int h = col10 >> 6, d = col10 & 63;
      bf16_t* Pt = (tns == 0) ? Pq : (tns == 1 ? Pk : Pv);
      bf16_t* bp = Pt + ((size_t)(hgRow + h) * PROWS + trow0) * 64 + d;
      float scl = (tns == 0) ? 0.125f : 1.f;
#pragma unroll
      for (int fi = 0; fi < 4; ++fi)
#pragma unroll
        for (int r = 0; r < 4; ++r)
          bp[(fi * 16 + r) * 64] = (bf16_t)(acc[fi][fj][r] * scl);
    }
  }
}

// ---------------------------------------------------------------- coarsen L0 -> levels 4..8 ONLY (L1-3 never materialized)
__global__ __launch_bounds__(256) void coarsen_lite(bf16_t* __restrict__ Pq,
                                                    bf16_t* __restrict__ Pk,
                                                    bf16_t* __restrict__ Pv) {
  __shared__ float l6s[4][64];
  const int poffA[9] = {0, 8192, 12288, 14336, 15360, 15872, 16128, 16256, 16320};
  const int hg = blockIdx.x >> 5, win = blockIdx.x & 31;
  const int tid = threadIdx.x;
  const int d8 = tid & 7, tb = tid >> 3, wv = tid >> 6;
  const size_t base = (size_t)hg * PROWS;
  const int r0 = win * 256 + tb * 8;

#pragma unroll 1
  for (int tensor = 0; tensor < 3; ++tensor) {
    bf16_t* P = (tensor == 0) ? Pq : (tensor == 1 ? Pk : Pv);
    const bool isv = (tensor == 2);
    float s3[8] = {}, t[8], o[8];
#pragma unroll
    for (int i = 0; i < 8; ++i) {
      load8f(P + (base + r0 + i) * 64 + d8 * 8, t);
#pragma unroll
      for (int e = 0; e < 8; ++e) s3[e] += t[e];
    }
    float s4[8], s5[8], s6[8];
#pragma unroll
    for (int e = 0; e < 8; ++e) s4[e] = s3[e] + __shfl_xor(s3[e], 8, 64);
    if ((tb & 1) == 0) {
      float sc = isv ? 1.f : 0.0625f;
#pragma unroll
      for (int e = 0; e < 8; ++e) o[e] = s4[e] * sc;
      store8f(P + (base + poffA[4] + win * 16 + (tb >> 1)) * 64 + d8 * 8, o);
    }
#pragma unroll
    for (int e = 0; e < 8; ++e) s5[e] = s4[e] + __shfl_xor(s4[e], 16, 64);
    if ((tb & 3) == 0) {
      float sc = isv ? 1.f : 0.03125f;
#pragma unroll
      for (int e = 0; e < 8; ++e) o[e] = s5[e] * sc;
      store8f(P + (base + poffA[5] + win * 8 + (tb >> 2)) * 64 + d8 * 8, o);
    }
#pragma unroll
    for (int e = 0; e < 8; ++e) s6[e] = s5[e] + __shfl_xor(s5[e], 32, 64);
    if ((tb & 7) == 0) {
      float sc = isv ? 1.f : 0.015625f;
#pragma unroll
      for (int e = 0; e < 8; ++e) { o[e] = s6[e] * sc; l6s[wv][d8 * 8 + e] = s6[e]; }
      store8f(P + (base + poffA[6] + win * 4 + wv) * 64 + d8 * 8, o);
    }
    __syncthreads();
    if (tid < 16) {
      int pr = tid >> 3, dd = tid & 7;
      float sc7 = isv ? 1.f : 0.0078125f;
#pragma unroll
      for (int e = 0; e < 8; ++e)
        o[e] = (l6s[2 * pr][dd * 8 + e] + l6s[2 * pr + 1][dd * 8 + e]) * sc7;
      store8f(P + (base + poffA[7] + win * 2 + pr) * 64 + dd * 8, o);
    }
    if (tid < 8) {
      float sc8 = isv ? 1.f : 0.00390625f;
#pragma unroll
      for (int e = 0; e < 8; ++e)
        o[e] = (l6s[0][d8 * 8 + e] + l6s[1][d8 * 8 + e] +
                l6s[2][d8 * 8 + e] + l6s[3][d8 * 8 + e]) * sc8;
      store8f(P + (base + poffA[8] + win) * 64 + d8 * 8, o);
    }
    __syncthreads();
  }
}

// ---------------------------------------------------------------- levels 4..8 attention (reads pyramid, y in place + Asum)
__global__ __launch_bounds__(256) void attn_hi(bf16_t* __restrict__ Pq,
                                               const bf16_t* __restrict__ Pk,
                                               const bf16_t* __restrict__ Pv,
                                               float* __restrict__ Asum) {
  const int poffA[9] = {0, 8192, 12288, 14336, 15360, 15872, 16128, 16256, 16320};
  const int tid = threadIdx.x;
  const int wv = tid >> 6, lane = tid & 63;
  const int lr = lane & 15, lg = lane >> 4;

  int bid = blockIdx.x * 4 + wv;            // 3968 problems (levels 4-8)
  int l = 4, cnt = 2048;
  while (bid >= cnt) { bid -= cnt; cnt >>= 1; ++l; }
  const int lg2nblk = 9 - l;
  const int blk = bid & ((1 << lg2nblk) - 1);
  const int hg = bid >> lg2nblk;
  const int kvblk = blk ^ 1;
  const size_t qbase = (size_t)hg * PROWS + poffA[l] + blk * 16;
  const size_t kvbase = (size_t)hg * PROWS + poffA[l] + kvblk * 16;

  f32x4 s = {};
#pragma unroll
  for (int c = 0; c < 2; ++c) {
    bf16x8 ak = *(const bf16x8*)(Pk + (kvbase + lr) * 64 + c * 32 + lg * 8);
    bf16x8 bq = *(const bf16x8*)(Pq + (qbase + lr) * 64 + c * 32 + lg * 8);
    s = __builtin_amdgcn_mfma_f32_16x16x32_bf16(ak, bq, s, 0, 0, 0);
  }
  float mx = fmaxf(fmaxf(s[0], s[1]), fmaxf(s[2], s[3]));
  mx = fmaxf(mx, __shfl_xor(mx, 16, 64));
  mx = fmaxf(mx, __shfl_xor(mx, 32, 64));
  float a[4]; float asum = 0.f;
#pragma unroll
  for (int r = 0; r < 4; ++r) { a[r] = (float)(bf16_t)__expf(s[r] - mx); asum += a[r]; }
  asum += __shfl_xor(asum, 16, 64);
  asum += __shfl_xor(asum, 32, 64);
  if (lg == 0) Asum[qbase + lr] = asum;

  const int src0 = (2 * lg) * 16 + lr;
  const int src1 = (2 * lg + 1) * 16 + lr;
  bf16x8 pa;
#pragma unroll
  for (int r = 0; r < 4; ++r) {
    float c0 = __shfl(a[r], src0, 64);
    float c1 = __shfl(a[r], src1, 64);
    pa[r]     = (lg < 2) ? (bf16_t)c0 : (bf16_t)0.f;
    pa[r + 4] = (lg < 2) ? (bf16_t)c1 : (bf16_t)0.f;
  }
#pragma unroll
  for (int dt = 0; dt < 4; ++dt) {
    bf16x8 vf;
    if (lg < 2) {
#pragma unroll
      for (int e = 0; e < 8; ++e) vf[e] = Pv[(kvbase + lg * 8 + e) * 64 + dt * 16 + lr];
    } else {
#pragma unroll
      for (int e = 0; e < 8; ++e) vf[e] = (bf16_t)0.f;
    }
    f32x4 y = __builtin_amdgcn_mfma_f32_16x16x32_bf16(pa, vf, (f32x4){}, 0, 0, 0);
#pragma unroll
    for (int r = 0; r < 4; ++r)
      Pq[(qbase + 4 * lg + r) * 64 + dt * 16 + lr] = (bf16_t)y[r];
  }
}

// ---------------------------------------------------------------- fused attn L0-3 + combine, L1-3 derived on the fly
__global__ __launch_bounds__(256) void attn_comb(const bf16_t* __restrict__ Pq,
                                                 const bf16_t* __restrict__ Pk,
                                                 const bf16_t* __restrict__ Pv,
                                                 const float* __restrict__ Ab,
                                                 bf16_t* __restrict__ attnb) {
  __shared__ __align__(16) bf16_t yl[480 * 72];   // L0@0 L1@256 L2@384 L3@448, stride 72
  __shared__ float asl[480];
  const int poffA[9] = {0, 8192, 12288, 14336, 15360, 15872, 16128, 16256, 16320};
  const int loffA[4] = {0, 256, 384, 448};
  const int hg = blockIdx.x >> 5, win = blockIdx.x & 31;
  const int tid = threadIdx.x;
  const int wv = tid >> 6, lane = tid & 63;
  const int lr = lane & 15, lg = lane >> 4;
  const size_t hb = (size_t)hg * PROWS;

  auto do_attn = [&](int l, int blkL) {
    const int blk = win * (16 >> l) + blkL;
    const int kvblk = l ? (blk ^ 1) : blk;
    const int lrow = loffA[l] + blkL * 16;
    const int q0 = (blk * 16 + lr) << l;
    const int k0 = (kvblk * 16 + lr) << l;
    const int kv0 = (kvblk * 16) << l;
    const float scl = 1.f / (float)(1 << l);

    f32x4 s = {};
#pragma unroll
    for (int c = 0; c < 2; ++c) {
      float fk[8] = {}, fq[8] = {}, t[8];
      for (int m = 0; m < (1 << l); ++m) {
        load8f(Pk + (hb + k0 + m) * 64 + c * 32 + lg * 8, t);
#pragma unroll
        for (int e = 0; e < 8; ++e) fk[e] += t[e];
        load8f(Pq + (hb + q0 + m) * 64 + c * 32 + lg * 8, t);
#pragma unroll
        for (int e = 0; e < 8; ++e) fq[e] += t[e];
      }
      bf16x8 ak, bq;
#pragma unroll
      for (int e = 0; e < 8; ++e) {
        ak[e] = (bf16_t)(fk[e] * scl);
        bq[e] = (bf16_t)(fq[e] * scl);
      }
      s = __builtin_amdgcn_mfma_f32_16x16x32_bf16(ak, bq, s, 0, 0, 0);
    }

    float mx = fmaxf(fmaxf(s[0], s[1]), fmaxf(s[2], s[3]));
    mx = fmaxf(mx, __shfl_xor(mx, 16, 64));
    mx = fmaxf(mx, __shfl_xor(mx, 32, 64));
    float a[4]; float asum = 0.f;
#pragma unroll
    for (int r = 0; r < 4; ++r) { a[r] = (float)(bf16_t)__expf(s[r] - mx); asum += a[r]; }
    asum += __shfl_xor(asum, 16, 64);
    asum += __shfl_xor(asum, 32, 64);
    if (lg == 0) asl[lrow + lr] = asum;

    if (l == 0) {
      const int src0 = (2 * lg) * 16 + lr;
      const int src1 = (2 * lg + 1) * 16 + lr;
      bf16x8 pa;
#pragma unroll
      for (int r = 0; r < 4; ++r) {
        float c0 = __shfl(a[r], src0, 64);
        float c1 = __shfl(a[r], src1, 64);
        pa[r]     = (lg < 2) ? (bf16_t)c0 : (bf16_t)0.f;
        pa[r + 4] = (lg < 2) ? (bf16_t)c1 : (bf16_t)0.f;
      }
#pragma unroll
      for (int dt = 0; dt < 4; ++dt) {
        bf16x8 vf;
        if (lg < 2) {
#pragma unroll
          for (int e = 0; e < 8; ++e) vf[e] = Pv[(hb + kv0 + lg * 8 + e) * 64 + dt * 16 + lr];
        } else {
#pragma unroll
          for (int e = 0; e < 8; ++e) vf[e] = (bf16_t)0.f;
        }
        f32x4 y = __builtin_amdgcn_mfma_f32_16x16x32_bf16(pa, vf, (f32x4){}, 0, 0, 0);
#pragma unroll
        for (int r = 0; r < 4; ++r)
          yl[(lrow + 4 * lg + r) * 72 + dt * 16 + lr] = (bf16_t)y[r];
      }
    } else {
      const int nch = 1 << (l - 1);
      bf16x8 pa[4];
      for (int ch = 0; ch < nch; ++ch) {
        if (l == 1) {
#pragma unroll
          for (int e = 0; e < 8; ++e) pa[ch][e] = (bf16_t)a[e >> 1];
        } else if (l == 2) {
          int src = (2 * ch + (lg >> 1)) * 16 + lr;
          float t0 = __shfl(a[0], src, 64), t1 = __shfl(a[1], src, 64);
          float t2 = __shfl(a[2], src, 64), t3 = __shfl(a[3], src, 64);
          float vlo = (lg & 1) ? t2 : t0;
          float vhi = (lg & 1) ? t3 : t1;
#pragma unroll
          for (int e = 0; e < 4; ++e) { pa[ch][e] = (bf16_t)vlo; pa[ch][e + 4] = (bf16_t)vhi; }
        } else {
          int src = ch * 16 + lr;
          float t0 = __shfl(a[0], src, 64), t1 = __shfl(a[1], src, 64);
          float t2 = __shfl(a[2], src, 64), t3 = __shfl(a[3], src, 64);
          float v01 = (lg & 1) ? t1 : t0;
          float v23 = (lg & 1) ? t3 : t2;
          float vv = (lg & 2) ? v23 : v01;
#pragma unroll
          for (int e = 0; e < 8; ++e) pa[ch][e] = (bf16_t)vv;
        }
      }
#pragma unroll
      for (int dt = 0; dt < 4; ++dt) {
        f32x4 y = {};
        for (int ch = 0; ch < nch; ++ch) {
          bf16x8 vf;
#pragma unroll
          for (int e = 0; e < 8; ++e)
            vf[e] = Pv[(hb + kv0 + ch * 32 + lg * 8 + e) * 64 + dt * 16 + lr];
          y = __builtin_amdgcn_mfma_f32_16x16x32_bf16(pa[ch], vf, y, 0, 0, 0);
        }
#pragma unroll
        for (int r = 0; r < 4; ++r)
          yl[(lrow + 4 * lg + r) * 72 + dt * 16 + lr] = (bf16_t)y[r];
      }
    }
  };

  do_attn(0, wv * 4 + 0); do_attn(0, wv * 4 + 1);
  do_attn(0, wv * 4 + 2); do_attn(0, wv * 4 + 3);
  do_attn(1, wv * 2 + 0); do_attn(1, wv * 2 + 1);
  do_attn(2, wv);
  if (wv < 2) do_attn(3, wv);
  __syncthreads();

  const int d8 = tid & 7, rg = tid >> 3;
#pragma unroll
  for (int i = 0; i < 8; ++i) {
    const int r = rg * 8 + i;
    const int t = win * 256 + r;
    float acc[8] = {};
    float asum = 0.f;
#pragma unroll
    for (int l = 0; l < 4; ++l) {
      const int row = loffA[l] + (r >> l);
      asum += asl[row];
      bf16x8 v = *(const bf16x8*)&yl[row * 72 + d8 * 8];
#pragma unroll
      for (int e = 0; e < 8; ++e) acc[e] += (float)v[e];
    }
#pragma unroll
    for (int l = 4; l < 9; ++l) {
      const size_t grow = hb + poffA[l] + (t >> l);
      asum += Ab[grow];
      bf16x8 v = *(const bf16x8*)(Pq + grow * 64 + d8 * 8);
#pragma unroll
      for (int e = 0; e < 8; ++e) acc[e] += (float)v[e];
    }
    const float inv = 1.f / (asum + 1e-8f);
    bf16x8 o;
#pragma unroll
    for (int e = 0; e < 8; ++e) o[e] = (bf16_t)(acc[e] * inv);
    *(bf16x8*)(attnb + ((size_t)(hg >> 4) * 8192 + t) * 1024 + (hg & 15) * 64 + d8 * 8) = o;
  }
}

// ---------------------------------------------------------------- launch
// Workspace (bytes), total 481,550,336 (~459.2 MiB):
//   Pq @ 0           127.75 MiB  [64][16352][64] bf16 (q; L4-8 y in place)
//   Pk @ 133955584   127.75 MiB
//   Pv @ 267911168   127.75 MiB
//   Ab @ 401866752   4 MiB       [64][16352] f32 Asum (L4-8 used)
//   woutT @ 406052864  2 MiB
//   x_bf @ 408150016  64 MiB     (dead after gemm1)
//   wqkvT @ 475258880 6 MiB      (dead after gemm1)
// Alias: attnb @ 408150016 over x_bf (dead after gemm1).
extern "C" void kernel_launch(void* const* d_in, const int* in_sizes, int n_in,
                              void* d_out, int out_size, void* d_ws, size_t ws_size,
                              hipStream_t stream) {
  const float* x = (const float*)d_in[0];
  const float* wqkv = (const float*)d_in[1];
  const float* wout = (const float*)d_in[2];
  const float* bout = (const float*)d_in[3];
  float* out = (float*)d_out;
  (void)in_sizes; (void)n_in; (void)out_size; (void)ws_size;

  char* base = (char*)d_ws;
  bf16_t* Pq    = (bf16_t*)(base + 0);
  bf16_t* Pk    = (bf16_t*)(base + 133955584);
  bf16_t* Pv    = (bf16_t*)(base + 267911168);
  float*  Ab    = (float*)(base + 401866752);
  bf16_t* woutT = (bf16_t*)(base + 406052864);
  bf16_t* x_bf  = (bf16_t*)(base + 408150016);
  bf16_t* wqkvT = (bf16_t*)(base + 475258880);
  bf16_t* attnb = (bf16_t*)(base + 408150016);   // alias over dead x_bf

  cvt_f32_to_bf16<<<16384, 256, 0, stream>>>(x, x_bf);
  transpose_to_bf16<<<dim3(96, 32), 256, 0, stream>>>(wqkv, wqkvT, 1024, 3072);
  transpose_to_bf16<<<dim3(32, 32), 256, 0, stream>>>(wout, woutT, 1024, 1024);

  // qkv GEMM: 128^2 tiles, 2 blocks/CU -> scatter into pyramid level 0
  gemm128d<0><<<6144, 256, 0, stream>>>(x_bf, wqkvT, nullptr, nullptr, Pq, Pk, Pv,
                                        3072, 24);

  coarsen_lite<<<2048, 256, 0, stream>>>(Pq, Pk, Pv);

  attn_hi<<<992, 256, 0, stream>>>(Pq, Pk, Pv, Ab);
  attn_comb<<<2048, 256, 0, stream>>>(Pq, Pk, Pv, Ab, attnb);

  // output GEMM: fp32 + bias
  gemm128d<1><<<2048, 256, 0, stream>>>(attnb, woutT, out, bout, nullptr, nullptr, nullptr,
                                        1024, 8);
}

// Round 12
// 542.467 us; speedup vs baseline: 1.1198x; 1.1198x over previous
//
#include <hip/hip_runtime.h>
#include <hip/hip_bf16.h>

typedef __bf16 bf16_t;
typedef bf16_t bf16x8 __attribute__((ext_vector_type(8)));
typedef float f32x4 __attribute__((ext_vector_type(4)));

// Pyramid layout: P[hg][16352][64] bf16, hg = b*16+h (64 head-groups).
// Row offsets per level l: {0,8192,12288,14336,15360,15872,16128,16256,16320}.
// Levels 1-3 are NEVER materialized (derived on the fly in attn_comb).
#define PROWS 16352

// ---------------------------------------------------------------- helpers
__device__ __forceinline__ void gl_lds16(const bf16_t* g, bf16_t* l) {
  __builtin_amdgcn_global_load_lds(
      (const __attribute__((address_space(1))) void*)g,
      (__attribute__((address_space(3))) void*)l,
      16, 0, 0);
}

__device__ __forceinline__ void load8f(const bf16_t* p, float* f) {
  bf16x8 v = *(const bf16x8*)p;
#pragma unroll
  for (int e = 0; e < 8; ++e) f[e] = (float)v[e];
}
__device__ __forceinline__ void store8f(bf16_t* p, const float* f) {
  bf16x8 v;
#pragma unroll
  for (int e = 0; e < 8; ++e) v[e] = (bf16_t)f[e];
  *(bf16x8*)p = v;
}

// ---------------------------------------------------------------- fp32 -> bf16 (x)
__global__ __launch_bounds__(256) void cvt_f32_to_bf16(const float* __restrict__ in,
                                                       bf16_t* __restrict__ o) {
  size_t gid = (size_t)blockIdx.x * 256 + threadIdx.x;
  const float4* p = (const float4*)in + gid * 2;
  float4 a = p[0], b = p[1];
  bf16x8 v;
  v[0] = (bf16_t)a.x; v[1] = (bf16_t)a.y; v[2] = (bf16_t)a.z; v[3] = (bf16_t)a.w;
  v[4] = (bf16_t)b.x; v[5] = (bf16_t)b.y; v[6] = (bf16_t)b.z; v[7] = (bf16_t)b.w;
  *(bf16x8*)(o + gid * 8) = v;
}

// ---------------------------------------------------------------- weight transpose + cast: w[K][N] -> wT[N][K] bf16
__global__ __launch_bounds__(256) void transpose_to_bf16(const float* __restrict__ w,
                                                         bf16_t* __restrict__ wT,
                                                         int K, int N) {
  __shared__ float t[32][33];
  int bx = blockIdx.x, by = blockIdx.y;
  int tx = threadIdx.x & 31, ty = threadIdx.x >> 5;
#pragma unroll
  for (int r = ty; r < 32; r += 8)
    t[r][tx] = w[(size_t)(by * 32 + r) * N + bx * 32 + tx];
  __syncthreads();
#pragma unroll
  for (int r = ty; r < 32; r += 8)
    wT[(size_t)(bx * 32 + r) * K + by * 32 + tx] = (bf16_t)t[tx][r];
}

// ---------------------------------------------------------------- 256x256 8-phase GEMM (non-persistent; round-4/5 proven body)
// C[M][N] = A[M][K=1024] @ Bt[N][K=1024]^T.  8 waves, BK=64, dbuf LDS 128 KiB,
// 4 phases/K-tile, counted vmcnt(8) at tile boundary only.
// T2 swizzle: k-slot' = k-slot ^ (row&7); linear gl_lds dest + pre-swizzled
// global source + swizzled ds_read (rule #21).
// EPI 0: pyramid scatter via LDS-bounce -> 1 KB coalesced stores (fixes the
//        315 MB -> 192 MB write amplification from 2 B scatter stores).
//        Wave band = 64 cols = exactly one (tns, head) -> per-wave constants.
// EPI 1: fp32 C + bias (direct stores, 64 B segments).
template <int EPI>
__global__ __launch_bounds__(512, 2) void gemm256(const bf16_t* __restrict__ A,
                                                  const bf16_t* __restrict__ Bt,
                                                  float* __restrict__ Cp,
                                                  const float* __restrict__ bias,
                                                  bf16_t* __restrict__ Pq,
                                                  bf16_t* __restrict__ Pk,
                                                  bf16_t* __restrict__ Pv,
                                                  int K, int ldc, int nTilesN) {
  __shared__ __align__(16) bf16_t As[2 * 256 * 64];   // K-loop dbuf; epilogue bounce
  __shared__ __align__(16) bf16_t Bs[2 * 256 * 64];
  const int tid = threadIdx.x;
  const int w = tid >> 6, lane = tid & 63;

  // T1: bijective XCD swizzle (gridDim.x % 8 == 0), ntile-fast decode.
  int nwg = gridDim.x;
  int chunk = nwg >> 3;
  int wgid = (blockIdx.x & 7) * chunk + (blockIdx.x >> 3);
  int mt = wgid / nTilesN, ntile = wgid % nTilesN;
  const int bm = mt * 256, bn = ntile * 256;

  const int wr = w >> 2, wc = w & 3;          // 2x4 wave grid; wave tile 128x64
  const int lr = lane & 15, lg = lane >> 4;
  const int sw = lr & 7;                      // T2 read-side XOR key
  const int nt = K >> 6;

  f32x4 acc[8][4] = {};

  auto stageHalf = [&](const bf16_t* __restrict__ G, int rbase, int kt, int ld,
                       bf16_t* lbuf, int h) {
#pragma unroll
    for (int j = 0; j < 2; ++j) {
      int b = j * 8 + w;
      int r3 = lane >> 3;
      int k8 = (lane & 7) ^ r3;               // T2 pre-swizzled source slot
      gl_lds16(G + (size_t)(rbase + h * 128 + b * 8 + r3) * ld + kt + k8 * 8,
               lbuf + h * 8192 + b * 512);
    }
  };

  // prologue: tiles 0 and 1 fully staged
  stageHalf(Bt, bn, 0, K, Bs, 0); stageHalf(Bt, bn, 0, K, Bs, 1);
  stageHalf(A, bm, 0, K, As, 0);  stageHalf(A, bm, 0, K, As, 1);
  if (nt > 1) {
    stageHalf(Bt, bn, 64, K, Bs + 16384, 0); stageHalf(Bt, bn, 64, K, Bs + 16384, 1);
    stageHalf(A, bm, 64, K, As + 16384, 0);  stageHalf(A, bm, 64, K, As + 16384, 1);
    asm volatile("s_waitcnt vmcnt(8)" ::: "memory");       // tile 0 landed
  } else {
    asm volatile("s_waitcnt vmcnt(0)" ::: "memory");
  }
  __syncthreads();

  for (int t = 0; t < nt; ++t) {
    const int c = t & 1;
    bf16_t* Abuf = As + c * 16384;
    bf16_t* Bbuf = Bs + c * 16384;
    const bool pf = (t + 2) < nt;
    const int kt2 = (t + 2) << 6;
    bf16x8 bfrag[4][2];

#pragma unroll
    for (int p = 0; p < 4; ++p) {
      bf16x8 afrag[2][2];
#pragma unroll
      for (int fi = 0; fi < 2; ++fi)
#pragma unroll
        for (int kk = 0; kk < 2; ++kk)
          afrag[fi][kk] = *(const bf16x8*)&Abuf[(wr * 128 + p * 32 + fi * 16 + lr) * 64 +
                                                (((kk * 4 + lg) ^ sw) * 8)];
      if (p == 0) {
#pragma unroll
        for (int fj = 0; fj < 4; ++fj)
#pragma unroll
          for (int kk = 0; kk < 2; ++kk)
            bfrag[fj][kk] = *(const bf16x8*)&Bbuf[(wc * 64 + fj * 16 + lr) * 64 +
                                                  (((kk * 4 + lg) ^ sw) * 8)];
      }
      if (pf) {
        if (p == 1) stageHalf(Bt, bn, kt2, K, Bbuf, 0);
        if (p == 2) stageHalf(Bt, bn, kt2, K, Bbuf, 1);
        if (p == 3) { stageHalf(A, bm, kt2, K, Abuf, 0); stageHalf(A, bm, kt2, K, Abuf, 1); }
      }
      __builtin_amdgcn_s_barrier();
      asm volatile("s_waitcnt lgkmcnt(0)" ::: "memory");
      __builtin_amdgcn_sched_barrier(0);
      __builtin_amdgcn_s_setprio(1);
#pragma unroll
      for (int kk = 0; kk < 2; ++kk)
#pragma unroll
        for (int fi = 0; fi < 2; ++fi)
#pragma unroll
          for (int fj = 0; fj < 4; ++fj)
            acc[p * 2 + fi][fj] = __builtin_amdgcn_mfma_f32_16x16x32_bf16(
                afrag[fi][kk], bfrag[fj][kk], acc[p * 2 + fi][fj], 0, 0, 0);
      __builtin_amdgcn_s_setprio(0);
      if (p == 3) {
        if (pf) asm volatile("s_waitcnt vmcnt(8)" ::: "memory");   // tile t+1 landed
        else    asm volatile("s_waitcnt vmcnt(0)" ::: "memory");   // tail drain
      }
      __builtin_amdgcn_s_barrier();
    }
  }

  // ---- epilogue (LDS is dead after the final barrier: non-persistent)
  if (EPI == 1) {
    float bv[4];
#pragma unroll
    for (int fj = 0; fj < 4; ++fj) bv[fj] = bias[bn + wc * 64 + fj * 16 + lr];
#pragma unroll
    for (int fi = 0; fi < 8; ++fi)
#pragma unroll
      for (int fj = 0; fj < 4; ++fj)
#pragma unroll
        for (int r = 0; r < 4; ++r) {
          int row = bm + wr * 128 + fi * 16 + lg * 4 + r;
          int col = bn + wc * 64 + fj * 16 + lr;
          Cp[(size_t)row * ldc + col] = acc[fi][fj][r] + bv[fj];
        }
  } else {
    // wave constants: band of 64 cols = one (tns, head); 256-row tile never
    // straddles the 8192-row hg boundary.
    const int tns = bn >> 10;
    const int h = ((bn & 1023) >> 6) + wc;
    const int hgRow = (bm >> 13) << 4;
    const int trow0 = (bm & 8191) + wr * 128;
    bf16_t* Pt = (tns == 0) ? Pq : (tns == 1 ? Pk : Pv);
    const float scl = (tns == 0) ? 0.125f : 1.f;
    bf16_t* lds = (w < 4) ? (As + w * 4608) : (Bs + (w - 4) * 4608);  // 64 rows x 72
    const size_t gbase = ((size_t)(hgRow + h) * PROWS + trow0) * 64;
#pragma unroll
    for (int half = 0; half < 2; ++half) {
#pragma unroll
      for (int fi4 = 0; fi4 < 4; ++fi4) {
        const int fi = half * 4 + fi4;
#pragma unroll
        for (int fj = 0; fj < 4; ++fj)
#pragma unroll
          for (int r = 0; r < 4; ++r)
            lds[(fi4 * 16 + lg * 4 + r) * 72 + fj * 16 + lr] =
                (bf16_t)(acc[fi][fj][r] * scl);
      }
      asm volatile("s_waitcnt lgkmcnt(0)" ::: "memory");   // writes visible to own wave reads
#pragma unroll
      for (int it = 0; it < 8; ++it) {
        const int row = it * 8 + (lane >> 3);
        bf16x8 v = *(const bf16x8*)&lds[row * 72 + (lane & 7) * 8];
        *(bf16x8*)(Pt + gbase + (size_t)(half * 64 + row) * 64 + (lane & 7) * 8) = v;
      }
      asm volatile("s_waitcnt lgkmcnt(0)" ::: "memory");   // reads retired before re-write
    }
  }
}

// ---------------------------------------------------------------- coarsen L0 -> levels 4..8 ONLY (L1-3 never materialized)
__global__ __launch_bounds__(256) void coarsen_lite(bf16_t* __restrict__ Pq,
                                                    bf16_t* __restrict__ Pk,
                                                    bf16_t* __restrict__ Pv) {
  __shared__ float l6s[4][64];
  const int poffA[9] = {0, 8192, 12288, 14336, 15360, 15872, 16128, 16256, 16320};
  const int hg = blockIdx.x >> 5, win = blockIdx.x & 31;
  const int tid = threadIdx.x;
  const int d8 = tid & 7, tb = tid >> 3, wv = tid >> 6;
  const size_t base = (size_t)hg * PROWS;
  const int r0 = win * 256 + tb * 8;

#pragma unroll 1
  for (int tensor = 0; tensor < 3; ++tensor) {
    bf16_t* P = (tensor == 0) ? Pq : (tensor == 1 ? Pk : Pv);
    const bool isv = (tensor == 2);
    float s3[8] = {}, t[8], o[8];
#pragma unroll
    for (int i = 0; i < 8; ++i) {
      load8f(P + (base + r0 + i) * 64 + d8 * 8, t);
#pragma unroll
      for (int e = 0; e < 8; ++e) s3[e] += t[e];
    }
    float s4[8], s5[8], s6[8];
#pragma unroll
    for (int e = 0; e < 8; ++e) s4[e] = s3[e] + __shfl_xor(s3[e], 8, 64);
    if ((tb & 1) == 0) {
      float sc = isv ? 1.f : 0.0625f;
#pragma unroll
      for (int e = 0; e < 8; ++e) o[e] = s4[e] * sc;
      store8f(P + (base + poffA[4] + win * 16 + (tb >> 1)) * 64 + d8 * 8, o);
    }
#pragma unroll
    for (int e = 0; e < 8; ++e) s5[e] = s4[e] + __shfl_xor(s4[e], 16, 64);
    if ((tb & 3) == 0) {
      float sc = isv ? 1.f : 0.03125f;
#pragma unroll
      for (int e = 0; e < 8; ++e) o[e] = s5[e] * sc;
      store8f(P + (base + poffA[5] + win * 8 + (tb >> 2)) * 64 + d8 * 8, o);
    }
#pragma unroll
    for (int e = 0; e < 8; ++e) s6[e] = s5[e] + __shfl_xor(s5[e], 32, 64);
    if ((tb & 7) == 0) {
      float sc = isv ? 1.f : 0.015625f;
#pragma unroll
      for (int e = 0; e < 8; ++e) { o[e] = s6[e] * sc; l6s[wv][d8 * 8 + e] = s6[e]; }
      store8f(P + (base + poffA[6] + win * 4 + wv) * 64 + d8 * 8, o);
    }
    __syncthreads();
    if (tid < 16) {
      int pr = tid >> 3, dd = tid & 7;
      float sc7 = isv ? 1.f : 0.0078125f;
#pragma unroll
      for (int e = 0; e < 8; ++e)
        o[e] = (l6s[2 * pr][dd * 8 + e] + l6s[2 * pr + 1][dd * 8 + e]) * sc7;
      store8f(P + (base + poffA[7] + win * 2 + pr) * 64 + dd * 8, o);
    }
    if (tid < 8) {
      float sc8 = isv ? 1.f : 0.00390625f;
#pragma unroll
      for (int e = 0; e < 8; ++e)
        o[e] = (l6s[0][d8 * 8 + e] + l6s[1][d8 * 8 + e] +
                l6s[2][d8 * 8 + e] + l6s[3][d8 * 8 + e]) * sc8;
      store8f(P + (base + poffA[8] + win) * 64 + d8 * 8, o);
    }
    __syncthreads();
  }
}

// ---------------------------------------------------------------- levels 4..8 attention (reads pyramid, y in place + Asum)
__global__ __launch_bounds__(256) void attn_hi(bf16_t* __restrict__ Pq,
                                               const bf16_t* __restrict__ Pk,
                                               const bf16_t* __restrict__ Pv,
                                               float* __restrict__ Asum) {
  const int poffA[9] = {0, 8192, 12288, 14336, 15360, 15872, 16128, 16256, 16320};
  const int tid = threadIdx.x;
  const int wv = tid >> 6, lane = tid & 63;
  const int lr = lane & 15, lg = lane >> 4;

  int bid = blockIdx.x * 4 + wv;            // 3968 problems (levels 4-8)
  int l = 4, cnt = 2048;
  while (bid >= cnt) { bid -= cnt; cnt >>= 1; ++l; }
  const int lg2nblk = 9 - l;
  const int blk = bid & ((1 << lg2nblk) - 1);
  const int hg = bid >> lg2nblk;
  const int kvblk = blk ^ 1;
  const size_t qbase = (size_t)hg * PROWS + poffA[l] + blk * 16;
  const size_t kvbase = (size_t)hg * PROWS + poffA[l] + kvblk * 16;

  f32x4 s = {};
#pragma unroll
  for (int c = 0; c < 2; ++c) {
    bf16x8 ak = *(const bf16x8*)(Pk + (kvbase + lr) * 64 + c * 32 + lg * 8);
    bf16x8 bq = *(const bf16x8*)(Pq + (qbase + lr) * 64 + c * 32 + lg * 8);
    s = __builtin_amdgcn_mfma_f32_16x16x32_bf16(ak, bq, s, 0, 0, 0);
  }
  float mx = fmaxf(fmaxf(s[0], s[1]), fmaxf(s[2], s[3]));
  mx = fmaxf(mx, __shfl_xor(mx, 16, 64));
  mx = fmaxf(mx, __shfl_xor(mx, 32, 64));
  float a[4]; float asum = 0.f;
#pragma unroll
  for (int r = 0; r < 4; ++r) { a[r] = (float)(bf16_t)__expf(s[r] - mx); asum += a[r]; }
  asum += __shfl_xor(asum, 16, 64);
  asum += __shfl_xor(asum, 32, 64);
  if (lg == 0) Asum[qbase + lr] = asum;

  const int src0 = (2 * lg) * 16 + lr;
  const int src1 = (2 * lg + 1) * 16 + lr;
  bf16x8 pa;
#pragma unroll
  for (int r = 0; r < 4; ++r) {
    float c0 = __shfl(a[r], src0, 64);
    float c1 = __shfl(a[r], src1, 64);
    pa[r]     = (lg < 2) ? (bf16_t)c0 : (bf16_t)0.f;
    pa[r + 4] = (lg < 2) ? (bf16_t)c1 : (bf16_t)0.f;
  }
#pragma unroll
  for (int dt = 0; dt < 4; ++dt) {
    bf16x8 vf;
    if (lg < 2) {
#pragma unroll
      for (int e = 0; e < 8; ++e) vf[e] = Pv[(kvbase + lg * 8 + e) * 64 + dt * 16 + lr];
    } else {
#pragma unroll
      for (int e = 0; e < 8; ++e) vf[e] = (bf16_t)0.f;
    }
    f32x4 y = __builtin_amdgcn_mfma_f32_16x16x32_bf16(pa, vf, (f32x4){}, 0, 0, 0);
#pragma unroll
    for (int r = 0; r < 4; ++r)
      Pq[(qbase + 4 * lg + r) * 64 + dt * 16 + lr] = (bf16_t)y[r];
  }
}

// ---------------------------------------------------------------- fused attn L0-3 + combine, L1-3 derived on the fly
__global__ __launch_bounds__(256) void attn_comb(const bf16_t* __restrict__ Pq,
                                                 const bf16_t* __restrict__ Pk,
                                                 const bf16_t* __restrict__ Pv,
                                                 const float* __restrict__ Ab,
                                                 bf16_t* __restrict__ attnb) {
  __shared__ __align__(16) bf16_t yl[480 * 72];   // L0@0 L1@256 L2@384 L3@448, stride 72
  __shared__ float asl[480];
  const int poffA[9] = {0, 8192, 12288, 14336, 15360, 15872, 16128, 16256, 16320};
  const int loffA[4] = {0, 256, 384, 448};
  const int hg = blockIdx.x >> 5, win = blockIdx.x & 31;
  const int tid = threadIdx.x;
  const int wv = tid >> 6, lane = tid & 63;
  const int lr = lane & 15, lg = lane >> 4;
  const size_t hb = (size_t)hg * PROWS;

  auto do_attn = [&](int l, int blkL) {
    const int blk = win * (16 >> l) + blkL;
    const int kvblk = l ? (blk ^ 1) : blk;
    const int lrow = loffA[l] + blkL * 16;
    const int q0 = (blk * 16 + lr) << l;
    const int k0 = (kvblk * 16 + lr) << l;
    const int kv0 = (kvblk * 16) << l;
    const float scl = 1.f / (float)(1 << l);

    f32x4 s = {};
#pragma unroll
    for (int c = 0; c < 2; ++c) {
      float fk[8] = {}, fq[8] = {}, t[8];
      for (int m = 0; m < (1 << l); ++m) {
        load8f(Pk + (hb + k0 + m) * 64 + c * 32 + lg * 8, t);
#pragma unroll
        for (int e = 0; e < 8; ++e) fk[e] += t[e];
        load8f(Pq + (hb + q0 + m) * 64 + c * 32 + lg * 8, t);
#pragma unroll
        for (int e = 0; e < 8; ++e) fq[e] += t[e];
      }
      bf16x8 ak, bq;
#pragma unroll
      for (int e = 0; e < 8; ++e) {
        ak[e] = (bf16_t)(fk[e] * scl);
        bq[e] = (bf16_t)(fq[e] * scl);
      }
      s = __builtin_amdgcn_mfma_f32_16x16x32_bf16(ak, bq, s, 0, 0, 0);
    }

    float mx = fmaxf(fmaxf(s[0], s[1]), fmaxf(s[2], s[3]));
    mx = fmaxf(mx, __shfl_xor(mx, 16, 64));
    mx = fmaxf(mx, __shfl_xor(mx, 32, 64));
    float a[4]; float asum = 0.f;
#pragma unroll
    for (int r = 0; r < 4; ++r) { a[r] = (float)(bf16_t)__expf(s[r] - mx); asum += a[r]; }
    asum += __shfl_xor(asum, 16, 64);
    asum += __shfl_xor(asum, 32, 64);
    if (lg == 0) asl[lrow + lr] = asum;

    if (l == 0) {
      const int src0 = (2 * lg) * 16 + lr;
      const int src1 = (2 * lg + 1) * 16 + lr;
      bf16x8 pa;
#pragma unroll
      for (int r = 0; r < 4; ++r) {
        float c0 = __shfl(a[r], src0, 64);
        float c1 = __shfl(a[r], src1, 64);
        pa[r]     = (lg < 2) ? (bf16_t)c0 : (bf16_t)0.f;
        pa[r + 4] = (lg < 2) ? (bf16_t)c1 : (bf16_t)0.f;
      }
#pragma unroll
      for (int dt = 0; dt < 4; ++dt) {
        bf16x8 vf;
        if (lg < 2) {
#pragma unroll
          for (int e = 0; e < 8; ++e) vf[e] = Pv[(hb + kv0 + lg * 8 + e) * 64 + dt * 16 + lr];
        } else {
#pragma unroll
          for (int e = 0; e < 8; ++e) vf[e] = (bf16_t)0.f;
        }
        f32x4 y = __builtin_amdgcn_mfma_f32_16x16x32_bf16(pa, vf, (f32x4){}, 0, 0, 0);
#pragma unroll
        for (int r = 0; r < 4; ++r)
          yl[(lrow + 4 * lg + r) * 72 + dt * 16 + lr] = (bf16_t)y[r];
      }
    } else {
      const int nch = 1 << (l - 1);
      bf16x8 pa[4];
      for (int ch = 0; ch < nch; ++ch) {
        if (l == 1) {
#pragma unroll
          for (int e = 0; e < 8; ++e) pa[ch][e] = (bf16_t)a[e >> 1];
        } else if (l == 2) {
          int src = (2 * ch + (lg >> 1)) * 16 + lr;
          float t0 = __shfl(a[0], src, 64), t1 = __shfl(a[1], src, 64);
          float t2 = __shfl(a[2], src, 64), t3 = __shfl(a[3], src, 64);
          float vlo = (lg & 1) ? t2 : t0;
          float vhi = (lg & 1) ? t3 : t1;
#pragma unroll
          for (int e = 0; e < 4; ++e) { pa[ch][e] = (bf16_t)vlo; pa[ch][e + 4] = (bf16_t)vhi; }
        } else {
          int src = ch * 16 + lr;
          float t0 = __shfl(a[0], src, 64), t1 = __shfl(a[1], src, 64);
          float t2 = __shfl(a[2], src, 64), t3 = __shfl(a[3], src, 64);
          float v01 = (lg & 1) ? t1 : t0;
          float v23 = (lg & 1) ? t3 : t2;
          float vv = (lg & 2) ? v23 : v01;
#pragma unroll
          for (int e = 0; e < 8; ++e) pa[ch][e] = (bf16_t)vv;
        }
      }
#pragma unroll
      for (int dt = 0; dt < 4; ++dt) {
        f32x4 y = {};
        for (int ch = 0; ch < nch; ++ch) {
          bf16x8 vf;
#pragma unroll
          for (int e = 0; e < 8; ++e)
            vf[e] = Pv[(hb + kv0 + ch * 32 + lg * 8 + e) * 64 + dt * 16 + lr];
          y = __builtin_amdgcn_mfma_f32_16x16x32_bf16(pa[ch], vf, y, 0, 0, 0);
        }
#pragma unroll
        for (int r = 0; r < 4; ++r)
          yl[(lrow + 4 * lg + r) * 72 + dt * 16 + lr] = (bf16_t)y[r];
      }
    }
  };

  do_attn(0, wv * 4 + 0); do_attn(0, wv * 4 + 1);
  do_attn(0, wv * 4 + 2); do_attn(0, wv * 4 + 3);
  do_attn(1, wv * 2 + 0); do_attn(1, wv * 2 + 1);
  do_attn(2, wv);
  if (wv < 2) do_attn(3, wv);
  __syncthreads();

  const int d8 = tid & 7, rg = tid >> 3;
#pragma unroll
  for (int i = 0; i < 8; ++i) {
    const int r = rg * 8 + i;
    const int t = win * 256 + r;
    float acc[8] = {};
    float asum = 0.f;
#pragma unroll
    for (int l = 0; l < 4; ++l) {
      const int row = loffA[l] + (r >> l);
      asum += asl[row];
      bf16x8 v = *(const bf16x8*)&yl[row * 72 + d8 * 8];
#pragma unroll
      for (int e = 0; e < 8; ++e) acc[e] += (float)v[e];
    }
#pragma unroll
    for (int l = 4; l < 9; ++l) {
      const size_t grow = hb + poffA[l] + (t >> l);
      asum += Ab[grow];
      bf16x8 v = *(const bf16x8*)(Pq + grow * 64 + d8 * 8);
#pragma unroll
      for (int e = 0; e < 8; ++e) acc[e] += (float)v[e];
    }
    const float inv = 1.f / (asum + 1e-8f);
    bf16x8 o;
#pragma unroll
    for (int e = 0; e < 8; ++e) o[e] = (bf16_t)(acc[e] * inv);
    *(bf16x8*)(attnb + ((size_t)(hg >> 4) * 8192 + t) * 1024 + (hg & 15) * 64 + d8 * 8) = o;
  }
}

// ---------------------------------------------------------------- launch
// Workspace (bytes), total 481,550,336 (~459.2 MiB):
//   Pq @ 0           127.75 MiB  [64][16352][64] bf16 (q; L4-8 y in place)
//   Pk @ 133955584   127.75 MiB
//   Pv @ 267911168   127.75 MiB
//   Ab @ 401866752   4 MiB       [64][16352] f32 Asum (L4-8 used)
//   woutT @ 406052864  2 MiB
//   x_bf @ 408150016  64 MiB     (dead after gemm1)
//   wqkvT @ 475258880 6 MiB      (dead after gemm1)
// Alias: attnb @ 408150016 over x_bf (dead after gemm1).
extern "C" void kernel_launch(void* const* d_in, const int* in_sizes, int n_in,
                              void* d_out, int out_size, void* d_ws, size_t ws_size,
                              hipStream_t stream) {
  const float* x = (const float*)d_in[0];
  const float* wqkv = (const float*)d_in[1];
  const float* wout = (const float*)d_in[2];
  const float* bout = (const float*)d_in[3];
  float* out = (float*)d_out;
  (void)in_sizes; (void)n_in; (void)out_size; (void)ws_size;

  char* base = (char*)d_ws;
  bf16_t* Pq    = (bf16_t*)(base + 0);
  bf16_t* Pk    = (bf16_t*)(base + 133955584);
  bf16_t* Pv    = (bf16_t*)(base + 267911168);
  float*  Ab    = (float*)(base + 401866752);
  bf16_t* woutT = (bf16_t*)(base + 406052864);
  bf16_t* x_bf  = (bf16_t*)(base + 408150016);
  bf16_t* wqkvT = (bf16_t*)(base + 475258880);
  bf16_t* attnb = (bf16_t*)(base + 408150016);   // alias over dead x_bf

  cvt_f32_to_bf16<<<16384, 256, 0, stream>>>(x, x_bf);
  transpose_to_bf16<<<dim3(96, 32), 256, 0, stream>>>(wqkv, wqkvT, 1024, 3072);
  transpose_to_bf16<<<dim3(32, 32), 256, 0, stream>>>(wout, woutT, 1024, 1024);

  // qkv GEMM (non-persistent 256^2) -> coalesced pyramid scatter
  gemm256<0><<<1536, 512, 0, stream>>>(x_bf, wqkvT, nullptr, nullptr, Pq, Pk, Pv,
                                       1024, 3072, 12);

  coarsen_lite<<<2048, 256, 0, stream>>>(Pq, Pk, Pv);

  attn_hi<<<992, 256, 0, stream>>>(Pq, Pk, Pv, Ab);
  attn_comb<<<2048, 256, 0, stream>>>(Pq, Pk, Pv, Ab, attnb);

  // output GEMM (non-persistent), fp32 + bias
  gemm256<1><<<512, 512, 0, stream>>>(attnb, woutT, out, bout, nullptr, nullptr, nullptr,
                                      1024, 1024, 4);
}

// Round 13
// 541.339 us; speedup vs baseline: 1.1222x; 1.0021x over previous
//
#include <hip/hip_runtime.h>
#include <hip/hip_bf16.h>

typedef __bf16 bf16_t;
typedef bf16_t bf16x8 __attribute__((ext_vector_type(8)));
typedef float f32x4 __attribute__((ext_vector_type(4)));

// Pyramid layout: P[hg][16352][64] bf16, hg = b*16+h (64 head-groups).
// Row offsets per level l: {0,8192,12288,14336,15360,15872,16128,16256,16320}.
// Levels 1-3 are NEVER materialized (derived on the fly in attn_comb).
#define PROWS 16352

// ---------------------------------------------------------------- helpers
__device__ __forceinline__ void gl_lds16(const bf16_t* g, bf16_t* l) {
  __builtin_amdgcn_global_load_lds(
      (const __attribute__((address_space(1))) void*)g,
      (__attribute__((address_space(3))) void*)l,
      16, 0, 0);
}

__device__ __forceinline__ void load8f(const bf16_t* p, float* f) {
  bf16x8 v = *(const bf16x8*)p;
#pragma unroll
  for (int e = 0; e < 8; ++e) f[e] = (float)v[e];
}
__device__ __forceinline__ void store8f(bf16_t* p, const float* f) {
  bf16x8 v;
#pragma unroll
  for (int e = 0; e < 8; ++e) v[e] = (bf16_t)f[e];
  *(bf16x8*)p = v;
}

// ---------------------------------------------------------------- fp32 -> bf16 (x)
__global__ __launch_bounds__(256) void cvt_f32_to_bf16(const float* __restrict__ in,
                                                       bf16_t* __restrict__ o) {
  size_t gid = (size_t)blockIdx.x * 256 + threadIdx.x;
  const float4* p = (const float4*)in + gid * 2;
  float4 a = p[0], b = p[1];
  bf16x8 v;
  v[0] = (bf16_t)a.x; v[1] = (bf16_t)a.y; v[2] = (bf16_t)a.z; v[3] = (bf16_t)a.w;
  v[4] = (bf16_t)b.x; v[5] = (bf16_t)b.y; v[6] = (bf16_t)b.z; v[7] = (bf16_t)b.w;
  *(bf16x8*)(o + gid * 8) = v;
}

// ---------------------------------------------------------------- weight transpose + cast: w[K][N] -> wT[N][K] bf16
__global__ __launch_bounds__(256) void transpose_to_bf16(const float* __restrict__ w,
                                                         bf16_t* __restrict__ wT,
                                                         int K, int N) {
  __shared__ float t[32][33];
  int bx = blockIdx.x, by = blockIdx.y;
  int tx = threadIdx.x & 31, ty = threadIdx.x >> 5;
#pragma unroll
  for (int r = ty; r < 32; r += 8)
    t[r][tx] = w[(size_t)(by * 32 + r) * N + bx * 32 + tx];
  __syncthreads();
#pragma unroll
  for (int r = ty; r < 32; r += 8)
    wT[(size_t)(bx * 32 + r) * K + by * 32 + tx] = (bf16_t)t[tx][r];
}

// ---------------------------------------------------------------- 256x256 8-phase GEMM (non-persistent; round-12 proven body)
// C[M][N] = A[M][K=1024] @ Bt[N][K=1024]^T.  8 waves, BK=64, dbuf LDS 128 KiB,
// 4 phases/K-tile, counted vmcnt(8) at tile boundary only.
// T2 swizzle: k-slot' = k-slot ^ (row&7); linear gl_lds dest + pre-swizzled
// global source + swizzled ds_read (rule #21).
// TILE MAP (EPI 0): L2-residency partition — staging is BW-bound (1.6 GB
//   staged vs 246 us = 6.5 TB/s = L3 ceiling). Each XCD owns a 32-M x 6-N
//   region, N-fast order: B working set 3 MB (L2-resident, reused every
//   M-round) + sliding A panels ~1 MB -> <= 4 MB L2 per XCD.
//   XCDs 0-3: ntile 0-5; XCDs 4-7: ntile 6-11; M split in 4 bands.
// TILE MAP (EPI 1): chunked XCD map (B = 2 MB already L2-fits).
// EPI 0: pyramid scatter via LDS-bounce -> 1 KB coalesced stores.
// EPI 1: fp32 C + bias.
template <int EPI>
__global__ __launch_bounds__(512, 2) void gemm256(const bf16_t* __restrict__ A,
                                                  const bf16_t* __restrict__ Bt,
                                                  float* __restrict__ Cp,
                                                  const float* __restrict__ bias,
                                                  bf16_t* __restrict__ Pq,
                                                  bf16_t* __restrict__ Pk,
                                                  bf16_t* __restrict__ Pv,
                                                  int K, int ldc, int nTilesN) {
  __shared__ __align__(16) bf16_t As[2 * 256 * 64];   // K-loop dbuf; epilogue bounce
  __shared__ __align__(16) bf16_t Bs[2 * 256 * 64];
  const int tid = threadIdx.x;
  const int w = tid >> 6, lane = tid & 63;

  int mt, ntile;
  if (EPI == 0) {
    // L2-resident map: grid 1536 = 8 XCDs x (32 M x 6 N), N-fast within XCD.
    const int x = blockIdx.x & 7;
    const int c = blockIdx.x >> 3;            // 0..191 within XCD
    mt = (x & 3) * 32 + c / 6;
    ntile = (x >> 2) * 6 + c % 6;
  } else {
    int nwg = gridDim.x;
    int chunk = nwg >> 3;
    int wgid = (blockIdx.x & 7) * chunk + (blockIdx.x >> 3);
    mt = wgid / nTilesN; ntile = wgid % nTilesN;
  }
  const int bm = mt * 256, bn = ntile * 256;

  const int wr = w >> 2, wc = w & 3;          // 2x4 wave grid; wave tile 128x64
  const int lr = lane & 15, lg = lane >> 4;
  const int sw = lr & 7;                      // T2 read-side XOR key
  const int nt = K >> 6;

  f32x4 acc[8][4] = {};

  auto stageHalf = [&](const bf16_t* __restrict__ G, int rbase, int kt, int ld,
                       bf16_t* lbuf, int h) {
#pragma unroll
    for (int j = 0; j < 2; ++j) {
      int b = j * 8 + w;
      int r3 = lane >> 3;
      int k8 = (lane & 7) ^ r3;               // T2 pre-swizzled source slot
      gl_lds16(G + (size_t)(rbase + h * 128 + b * 8 + r3) * ld + kt + k8 * 8,
               lbuf + h * 8192 + b * 512);
    }
  };

  // prologue: tiles 0 and 1 fully staged
  stageHalf(Bt, bn, 0, K, Bs, 0); stageHalf(Bt, bn, 0, K, Bs, 1);
  stageHalf(A, bm, 0, K, As, 0);  stageHalf(A, bm, 0, K, As, 1);
  if (nt > 1) {
    stageHalf(Bt, bn, 64, K, Bs + 16384, 0); stageHalf(Bt, bn, 64, K, Bs + 16384, 1);
    stageHalf(A, bm, 64, K, As + 16384, 0);  stageHalf(A, bm, 64, K, As + 16384, 1);
    asm volatile("s_waitcnt vmcnt(8)" ::: "memory");       // tile 0 landed
  } else {
    asm volatile("s_waitcnt vmcnt(0)" ::: "memory");
  }
  __syncthreads();

  for (int t = 0; t < nt; ++t) {
    const int c = t & 1;
    bf16_t* Abuf = As + c * 16384;
    bf16_t* Bbuf = Bs + c * 16384;
    const bool pf = (t + 2) < nt;
    const int kt2 = (t + 2) << 6;
    bf16x8 bfrag[4][2];

#pragma unroll
    for (int p = 0; p < 4; ++p) {
      bf16x8 afrag[2][2];
#pragma unroll
      for (int fi = 0; fi < 2; ++fi)
#pragma unroll
        for (int kk = 0; kk < 2; ++kk)
          afrag[fi][kk] = *(const bf16x8*)&Abuf[(wr * 128 + p * 32 + fi * 16 + lr) * 64 +
                                                (((kk * 4 + lg) ^ sw) * 8)];
      if (p == 0) {
#pragma unroll
        for (int fj = 0; fj < 4; ++fj)
#pragma unroll
          for (int kk = 0; kk < 2; ++kk)
            bfrag[fj][kk] = *(const bf16x8*)&Bbuf[(wc * 64 + fj * 16 + lr) * 64 +
                                                  (((kk * 4 + lg) ^ sw) * 8)];
      }
      if (pf) {
        if (p == 1) stageHalf(Bt, bn, kt2, K, Bbuf, 0);
        if (p == 2) stageHalf(Bt, bn, kt2, K, Bbuf, 1);
        if (p == 3) { stageHalf(A, bm, kt2, K, Abuf, 0); stageHalf(A, bm, kt2, K, Abuf, 1); }
      }
      __builtin_amdgcn_s_barrier();
      asm volatile("s_waitcnt lgkmcnt(0)" ::: "memory");
      __builtin_amdgcn_sched_barrier(0);
      __builtin_amdgcn_s_setprio(1);
#pragma unroll
      for (int kk = 0; kk < 2; ++kk)
#pragma unroll
        for (int fi = 0; fi < 2; ++fi)
#pragma unroll
          for (int fj = 0; fj < 4; ++fj)
            acc[p * 2 + fi][fj] = __builtin_amdgcn_mfma_f32_16x16x32_bf16(
                afrag[fi][kk], bfrag[fj][kk], acc[p * 2 + fi][fj], 0, 0, 0);
      __builtin_amdgcn_s_setprio(0);
      if (p == 3) {
        if (pf) asm volatile("s_waitcnt vmcnt(8)" ::: "memory");   // tile t+1 landed
        else    asm volatile("s_waitcnt vmcnt(0)" ::: "memory");   // tail drain
      }
      __builtin_amdgcn_s_barrier();
    }
  }

  // ---- epilogue (LDS is dead after the final barrier: non-persistent)
  if (EPI == 1) {
    float bv[4];
#pragma unroll
    for (int fj = 0; fj < 4; ++fj) bv[fj] = bias[bn + wc * 64 + fj * 16 + lr];
#pragma unroll
    for (int fi = 0; fi < 8; ++fi)
#pragma unroll
      for (int fj = 0; fj < 4; ++fj)
#pragma unroll
        for (int r = 0; r < 4; ++r) {
          int row = bm + wr * 128 + fi * 16 + lg * 4 + r;
          int col = bn + wc * 64 + fj * 16 + lr;
          Cp[(size_t)row * ldc + col] = acc[fi][fj][r] + bv[fj];
        }
  } else {
    // wave constants: band of 64 cols = one (tns, head); 256-row tile never
    // straddles the 8192-row hg boundary.
    const int tns = bn >> 10;
    const int h = ((bn & 1023) >> 6) + wc;
    const int hgRow = (bm >> 13) << 4;
    const int trow0 = (bm & 8191) + wr * 128;
    bf16_t* Pt = (tns == 0) ? Pq : (tns == 1 ? Pk : Pv);
    const float scl = (tns == 0) ? 0.125f : 1.f;
    bf16_t* lds = (w < 4) ? (As + w * 4608) : (Bs + (w - 4) * 4608);  // 64 rows x 72
    const size_t gbase = ((size_t)(hgRow + h) * PROWS + trow0) * 64;
#pragma unroll
    for (int half = 0; half < 2; ++half) {
#pragma unroll
      for (int fi4 = 0; fi4 < 4; ++fi4) {
        const int fi = half * 4 + fi4;
#pragma unroll
        for (int fj = 0; fj < 4; ++fj)
#pragma unroll
          for (int r = 0; r < 4; ++r)
            lds[(fi4 * 16 + lg * 4 + r) * 72 + fj * 16 + lr] =
                (bf16_t)(acc[fi][fj][r] * scl);
      }
      asm volatile("s_waitcnt lgkmcnt(0)" ::: "memory");   // writes visible to own wave reads
#pragma unroll
      for (int it = 0; it < 8; ++it) {
        const int row = it * 8 + (lane >> 3);
        bf16x8 v = *(const bf16x8*)&lds[row * 72 + (lane & 7) * 8];
        *(bf16x8*)(Pt + gbase + (size_t)(half * 64 + row) * 64 + (lane & 7) * 8) = v;
      }
      asm volatile("s_waitcnt lgkmcnt(0)" ::: "memory");   // reads retired before re-write
    }
  }
}

// ---------------------------------------------------------------- coarsen L0 -> levels 4..8 ONLY (L1-3 never materialized)
__global__ __launch_bounds__(256) void coarsen_lite(bf16_t* __restrict__ Pq,
                                                    bf16_t* __restrict__ Pk,
                                                    bf16_t* __restrict__ Pv) {
  __shared__ float l6s[4][64];
  const int poffA[9] = {0, 8192, 12288, 14336, 15360, 15872, 16128, 16256, 16320};
  const int hg = blockIdx.x >> 5, win = blockIdx.x & 31;
  const int tid = threadIdx.x;
  const int d8 = tid & 7, tb = tid >> 3, wv = tid >> 6;
  const size_t base = (size_t)hg * PROWS;
  const int r0 = win * 256 + tb * 8;

#pragma unroll 1
  for (int tensor = 0; tensor < 3; ++tensor) {
    bf16_t* P = (tensor == 0) ? Pq : (tensor == 1 ? Pk : Pv);
    const bool isv = (tensor == 2);
    float s3[8] = {}, t[8], o[8];
#pragma unroll
    for (int i = 0; i < 8; ++i) {
      load8f(P + (base + r0 + i) * 64 + d8 * 8, t);
#pragma unroll
      for (int e = 0; e < 8; ++e) s3[e] += t[e];
    }
    float s4[8], s5[8], s6[8];
#pragma unroll
    for (int e = 0; e < 8; ++e) s4[e] = s3[e] + __shfl_xor(s3[e], 8, 64);
    if ((tb & 1) == 0) {
      float sc = isv ? 1.f : 0.0625f;
#pragma unroll
      for (int e = 0; e < 8; ++e) o[e] = s4[e] * sc;
      store8f(P + (base + poffA[4] + win * 16 + (tb >> 1)) * 64 + d8 * 8, o);
    }
#pragma unroll
    for (int e = 0; e < 8; ++e) s5[e] = s4[e] + __shfl_xor(s4[e], 16, 64);
    if ((tb & 3) == 0) {
      float sc = isv ? 1.f : 0.03125f;
#pragma unroll
      for (int e = 0; e < 8; ++e) o[e] = s5[e] * sc;
      store8f(P + (base + poffA[5] + win * 8 + (tb >> 2)) * 64 + d8 * 8, o);
    }
#pragma unroll
    for (int e = 0; e < 8; ++e) s6[e] = s5[e] + __shfl_xor(s5[e], 32, 64);
    if ((tb & 7) == 0) {
      float sc = isv ? 1.f : 0.015625f;
#pragma unroll
      for (int e = 0; e < 8; ++e) { o[e] = s6[e] * sc; l6s[wv][d8 * 8 + e] = s6[e]; }
      store8f(P + (base + poffA[6] + win * 4 + wv) * 64 + d8 * 8, o);
    }
    __syncthreads();
    if (tid < 16) {
      int pr = tid >> 3, dd = tid & 7;
      float sc7 = isv ? 1.f : 0.0078125f;
#pragma unroll
      for (int e = 0; e < 8; ++e)
        o[e] = (l6s[2 * pr][dd * 8 + e] + l6s[2 * pr + 1][dd * 8 + e]) * sc7;
      store8f(P + (base + poffA[7] + win * 2 + pr) * 64 + dd * 8, o);
    }
    if (tid < 8) {
      float sc8 = isv ? 1.f : 0.00390625f;
#pragma unroll
      for (int e = 0; e < 8; ++e)
        o[e] = (l6s[0][d8 * 8 + e] + l6s[1][d8 * 8 + e] +
                l6s[2][d8 * 8 + e] + l6s[3][d8 * 8 + e]) * sc8;
      store8f(P + (base + poffA[8] + win) * 64 + d8 * 8, o);
    }
    __syncthreads();
  }
}

// ---------------------------------------------------------------- levels 4..8 attention (reads pyramid, y in place + Asum)
__global__ __launch_bounds__(256) void attn_hi(bf16_t* __restrict__ Pq,
                                               const bf16_t* __restrict__ Pk,
                                               const bf16_t* __restrict__ Pv,
                                               float* __restrict__ Asum) {
  const int poffA[9] = {0, 8192, 12288, 14336, 15360, 15872, 16128, 16256, 16320};
  const int tid = threadIdx.x;
  const int wv = tid >> 6, lane = tid & 63;
  const int lr = lane & 15, lg = lane >> 4;

  int bid = blockIdx.x * 4 + wv;            // 3968 problems (levels 4-8)
  int l = 4, cnt = 2048;
  while (bid >= cnt) { bid -= cnt; cnt >>= 1; ++l; }
  const int lg2nblk = 9 - l;
  const int blk = bid & ((1 << lg2nblk) - 1);
  const int hg = bid >> lg2nblk;
  const int kvblk = blk ^ 1;
  const size_t qbase = (size_t)hg * PROWS + poffA[l] + blk * 16;
  const size_t kvbase = (size_t)hg * PROWS + poffA[l] + kvblk * 16;

  f32x4 s = {};
#pragma unroll
  for (int c = 0; c < 2; ++c) {
    bf16x8 ak = *(const bf16x8*)(Pk + (kvbase + lr) * 64 + c * 32 + lg * 8);
    bf16x8 bq = *(const bf16x8*)(Pq + (qbase + lr) * 64 + c * 32 + lg * 8);
    s = __builtin_amdgcn_mfma_f32_16x16x32_bf16(ak, bq, s, 0, 0, 0);
  }
  float mx = fmaxf(fmaxf(s[0], s[1]), fmaxf(s[2], s[3]));
  mx = fmaxf(mx, __shfl_xor(mx, 16, 64));
  mx = fmaxf(mx, __shfl_xor(mx, 32, 64));
  float a[4]; float asum = 0.f;
#pragma unroll
  for (int r = 0; r < 4; ++r) { a[r] = (float)(bf16_t)__expf(s[r] - mx); asum += a[r]; }
  asum += __shfl_xor(asum, 16, 64);
  asum += __shfl_xor(asum, 32, 64);
  if (lg == 0) Asum[qbase + lr] = asum;

  const int src0 = (2 * lg) * 16 + lr;
  const int src1 = (2 * lg + 1) * 16 + lr;
  bf16x8 pa;
#pragma unroll
  for (int r = 0; r < 4; ++r) {
    float c0 = __shfl(a[r], src0, 64);
    float c1 = __shfl(a[r], src1, 64);
    pa[r]     = (lg < 2) ? (bf16_t)c0 : (bf16_t)0.f;
    pa[r + 4] = (lg < 2) ? (bf16_t)c1 : (bf16_t)0.f;
  }
#pragma unroll
  for (int dt = 0; dt < 4; ++dt) {
    bf16x8 vf;
    if (lg < 2) {
#pragma unroll
      for (int e = 0; e < 8; ++e) vf[e] = Pv[(kvbase + lg * 8 + e) * 64 + dt * 16 + lr];
    } else {
#pragma unroll
      for (int e = 0; e < 8; ++e) vf[e] = (bf16_t)0.f;
    }
    f32x4 y = __builtin_amdgcn_mfma_f32_16x16x32_bf16(pa, vf, (f32x4){}, 0, 0, 0);
#pragma unroll
    for (int r = 0; r < 4; ++r)
      Pq[(qbase + 4 * lg + r) * 64 + dt * 16 + lr] = (bf16_t)y[r];
  }
}

// ---------------------------------------------------------------- fused attn L0-3 + combine, L1-3 derived on the fly
__global__ __launch_bounds__(256) void attn_comb(const bf16_t* __restrict__ Pq,
                                                 const bf16_t* __restrict__ Pk,
                                                 const bf16_t* __restrict__ Pv,
                                                 const float* __restrict__ Ab,
                                                 bf16_t* __restrict__ attnb) {
  __shared__ __align__(16) bf16_t yl[480 * 72];   // L0@0 L1@256 L2@384 L3@448, stride 72
  __shared__ float asl[480];
  const int poffA[9] = {0, 8192, 12288, 14336, 15360, 15872, 16128, 16256, 16320};
  const int loffA[4] = {0, 256, 384, 448};
  const int hg = blockIdx.x >> 5, win = blockIdx.x & 31;
  const int tid = threadIdx.x;
  const int wv = tid >> 6, lane = tid & 63;
  const int lr = lane & 15, lg = lane >> 4;
  const size_t hb = (size_t)hg * PROWS;

  auto do_attn = [&](int l, int blkL) {
    const int blk = win * (16 >> l) + blkL;
    const int kvblk = l ? (blk ^ 1) : blk;
    const int lrow = loffA[l] + blkL * 16;
    const int q0 = (blk * 16 + lr) << l;
    const int k0 = (kvblk * 16 + lr) << l;
    const int kv0 = (kvblk * 16) << l;
    const float scl = 1.f / (float)(1 << l);

    f32x4 s = {};
#pragma unroll
    for (int c = 0; c < 2; ++c) {
      float fk[8] = {}, fq[8] = {}, t[8];
      for (int m = 0; m < (1 << l); ++m) {
        load8f(Pk + (hb + k0 + m) * 64 + c * 32 + lg * 8, t);
#pragma unroll
        for (int e = 0; e < 8; ++e) fk[e] += t[e];
        load8f(Pq + (hb + q0 + m) * 64 + c * 32 + lg * 8, t);
#pragma unroll
        for (int e = 0; e < 8; ++e) fq[e] += t[e];
      }
      bf16x8 ak, bq;
#pragma unroll
      for (int e = 0; e < 8; ++e) {
        ak[e] = (bf16_t)(fk[e] * scl);
        bq[e] = (bf16_t)(fq[e] * scl);
      }
      s = __builtin_amdgcn_mfma_f32_16x16x32_bf16(ak, bq, s, 0, 0, 0);
    }

    float mx = fmaxf(fmaxf(s[0], s[1]), fmaxf(s[2], s[3]));
    mx = fmaxf(mx, __shfl_xor(mx, 16, 64));
    mx = fmaxf(mx, __shfl_xor(mx, 32, 64));
    float a[4]; float asum = 0.f;
#pragma unroll
    for (int r = 0; r < 4; ++r) { a[r] = (float)(bf16_t)__expf(s[r] - mx); asum += a[r]; }
    asum += __shfl_xor(asum, 16, 64);
    asum += __shfl_xor(asum, 32, 64);
    if (lg == 0) asl[lrow + lr] = asum;

    if (l == 0) {
      const int src0 = (2 * lg) * 16 + lr;
      const int src1 = (2 * lg + 1) * 16 + lr;
      bf16x8 pa;
#pragma unroll
      for (int r = 0; r < 4; ++r) {
        float c0 = __shfl(a[r], src0, 64);
        float c1 = __shfl(a[r], src1, 64);
        pa[r]     = (lg < 2) ? (bf16_t)c0 : (bf16_t)0.f;
        pa[r + 4] = (lg < 2) ? (bf16_t)c1 : (bf16_t)0.f;
      }
#pragma unroll
      for (int dt = 0; dt < 4; ++dt) {
        bf16x8 vf;
        if (lg < 2) {
#pragma unroll
          for (int e = 0; e < 8; ++e) vf[e] = Pv[(hb + kv0 + lg * 8 + e) * 64 + dt * 16 + lr];
        } else {
#pragma unroll
          for (int e = 0; e < 8; ++e) vf[e] = (bf16_t)0.f;
        }
        f32x4 y = __builtin_amdgcn_mfma_f32_16x16x32_bf16(pa, vf, (f32x4){}, 0, 0, 0);
#pragma unroll
        for (int r = 0; r < 4; ++r)
          yl[(lrow + 4 * lg + r) * 72 + dt * 16 + lr] = (bf16_t)y[r];
      }
    } else {
      const int nch = 1 << (l - 1);
      bf16x8 pa[4];
      for (int ch = 0; ch < nch; ++ch) {
        if (l == 1) {
#pragma unroll
          for (int e = 0; e < 8; ++e) pa[ch][e] = (bf16_t)a[e >> 1];
        } else if (l == 2) {
          int src = (2 * ch + (lg >> 1)) * 16 + lr;
          float t0 = __shfl(a[0], src, 64), t1 = __shfl(a[1], src, 64);
          float t2 = __shfl(a[2], src, 64), t3 = __shfl(a[3], src, 64);
          float vlo = (lg & 1) ? t2 : t0;
          float vhi = (lg & 1) ? t3 : t1;
#pragma unroll
          for (int e = 0; e < 4; ++e) { pa[ch][e] = (bf16_t)vlo; pa[ch][e + 4] = (bf16_t)vhi; }
        } else {
          int src = ch * 16 + lr;
          float t0 = __shfl(a[0], src, 64), t1 = __shfl(a[1], src, 64);
          float t2 = __shfl(a[2], src, 64), t3 = __shfl(a[3], src, 64);
          float v01 = (lg & 1) ? t1 : t0;
          float v23 = (lg & 1) ? t3 : t2;
          float vv = (lg & 2) ? v23 : v01;
#pragma unroll
          for (int e = 0; e < 8; ++e) pa[ch][e] = (bf16_t)vv;
        }
      }
#pragma unroll
      for (int dt = 0; dt < 4; ++dt) {
        f32x4 y = {};
        for (int ch = 0; ch < nch; ++ch) {
          bf16x8 vf;
#pragma unroll
          for (int e = 0; e < 8; ++e)
            vf[e] = Pv[(hb + kv0 + ch * 32 + lg * 8 + e) * 64 + dt * 16 + lr];
          y = __builtin_amdgcn_mfma_f32_16x16x32_bf16(pa[ch], vf, y, 0, 0, 0);
        }
#pragma unroll
        for (int r = 0; r < 4; ++r)
          yl[(lrow + 4 * lg + r) * 72 + dt * 16 + lr] = (bf16_t)y[r];
      }
    }
  };

  do_attn(0, wv * 4 + 0); do_attn(0, wv * 4 + 1);
  do_attn(0, wv * 4 + 2); do_attn(0, wv * 4 + 3);
  do_attn(1, wv * 2 + 0); do_attn(1, wv * 2 + 1);
  do_attn(2, wv);
  if (wv < 2) do_attn(3, wv);
  __syncthreads();

  const int d8 = tid & 7, rg = tid >> 3;
#pragma unroll
  for (int i = 0; i < 8; ++i) {
    const int r = rg * 8 + i;
    const int t = win * 256 + r;
    float acc[8] = {};
    float asum = 0.f;
#pragma unroll
    for (int l = 0; l < 4; ++l) {
      const int row = loffA[l] + (r >> l);
      asum += asl[row];
      bf16x8 v = *(const bf16x8*)&yl[row * 72 + d8 * 8];
#pragma unroll
      for (int e = 0; e < 8; ++e) acc[e] += (float)v[e];
    }
#pragma unroll
    for (int l = 4; l < 9; ++l) {
      const size_t grow = hb + poffA[l] + (t >> l);
      asum += Ab[grow];
      bf16x8 v = *(const bf16x8*)(Pq + grow * 64 + d8 * 8);
#pragma unroll
      for (int e = 0; e < 8; ++e) acc[e] += (float)v[e];
    }
    const float inv = 1.f / (asum + 1e-8f);
    bf16x8 o;
#pragma unroll
    for (int e = 0; e < 8; ++e) o[e] = (bf16_t)(acc[e] * inv);
    *(bf16x8*)(attnb + ((size_t)(hg >> 4) * 8192 + t) * 1024 + (hg & 15) * 64 + d8 * 8) = o;
  }
}

// ---------------------------------------------------------------- launch
// Workspace (bytes), total 481,550,336 (~459.2 MiB):
//   Pq @ 0           127.75 MiB  [64][16352][64] bf16 (q; L4-8 y in place)
//   Pk @ 133955584   127.75 MiB
//   Pv @ 267911168   127.75 MiB
//   Ab @ 401866752   4 MiB       [64][16352] f32 Asum (L4-8 used)
//   woutT @ 406052864  2 MiB
//   x_bf @ 408150016  64 MiB     (dead after gemm1)
//   wqkvT @ 475258880 6 MiB      (dead after gemm1)
// Alias: attnb @ 408150016 over x_bf (dead after gemm1).
extern "C" void kernel_launch(void* const* d_in, const int* in_sizes, int n_in,
                              void* d_out, int out_size, void* d_ws, size_t ws_size,
                              hipStream_t stream) {
  const float* x = (const float*)d_in[0];
  const float* wqkv = (const float*)d_in[1];
  const float* wout = (const float*)d_in[2];
  const float* bout = (const float*)d_in[3];
  float* out = (float*)d_out;
  (void)in_sizes; (void)n_in; (void)out_size; (void)ws_size;

  char* base = (char*)d_ws;
  bf16_t* Pq    = (bf16_t*)(base + 0);
  bf16_t* Pk    = (bf16_t*)(base + 133955584);
  bf16_t* Pv    = (bf16_t*)(base + 267911168);
  float*  Ab    = (float*)(base + 401866752);
  bf16_t* woutT = (bf16_t*)(base + 406052864);
  bf16_t* x_bf  = (bf16_t*)(base + 408150016);
  bf16_t* wqkvT = (bf16_t*)(base + 475258880);
  bf16_t* attnb = (bf16_t*)(base + 408150016);   // alias over dead x_bf

  cvt_f32_to_bf16<<<16384, 256, 0, stream>>>(x, x_bf);
  transpose_to_bf16<<<dim3(96, 32), 256, 0, stream>>>(wqkv, wqkvT, 1024, 3072);
  transpose_to_bf16<<<dim3(32, 32), 256, 0, stream>>>(wout, woutT, 1024, 1024);

  // qkv GEMM (non-persistent 256^2, L2-resident tile map) -> coalesced pyramid scatter
  gemm256<0><<<1536, 512, 0, stream>>>(x_bf, wqkvT, nullptr, nullptr, Pq, Pk, Pv,
                                       1024, 3072, 12);

  coarsen_lite<<<2048, 256, 0, stream>>>(Pq, Pk, Pv);

  attn_hi<<<992, 256, 0, stream>>>(Pq, Pk, Pv, Ab);
  attn_comb<<<2048, 256, 0, stream>>>(Pq, Pk, Pv, Ab, attnb);

  // output GEMM (non-persistent), fp32 + bias
  gemm256<1><<<512, 512, 0, stream>>>(attnb, woutT, out, bout, nullptr, nullptr, nullptr,
                                      1024, 1024, 4);
}

// Round 14
// 514.102 us; speedup vs baseline: 1.1816x; 1.0530x over previous
//
#include <hip/hip_runtime.h>
#include <hip/hip_bf16.h>

typedef __bf16 bf16_t;
typedef bf16_t bf16x8 __attribute__((ext_vector_type(8)));
typedef float f32x4 __attribute__((ext_vector_type(4)));

// Pyramid layout: P[hg][16352][64] bf16, hg = b*16+h (64 head-groups).
// Row offsets per level l: {0,8192,12288,14336,15360,15872,16128,16256,16320}.
// Levels 1-3 are NEVER materialized (derived on the fly in attn_comb).
// Levels 4-8 are built in gemm1's epilogue from f32 accumulators.
#define PROWS 16352

// ---------------------------------------------------------------- helpers
__device__ __forceinline__ void gl_lds16(const bf16_t* g, bf16_t* l) {
  __builtin_amdgcn_global_load_lds(
      (const __attribute__((address_space(1))) void*)g,
      (__attribute__((address_space(3))) void*)l,
      16, 0, 0);
}

__device__ __forceinline__ void load8f(const bf16_t* p, float* f) {
  bf16x8 v = *(const bf16x8*)p;
#pragma unroll
  for (int e = 0; e < 8; ++e) f[e] = (float)v[e];
}

// ---------------------------------------------------------------- fp32 -> bf16 (x)
__global__ __launch_bounds__(256) void cvt_f32_to_bf16(const float* __restrict__ in,
                                                       bf16_t* __restrict__ o) {
  size_t gid = (size_t)blockIdx.x * 256 + threadIdx.x;
  const float4* p = (const float4*)in + gid * 2;
  float4 a = p[0], b = p[1];
  bf16x8 v;
  v[0] = (bf16_t)a.x; v[1] = (bf16_t)a.y; v[2] = (bf16_t)a.z; v[3] = (bf16_t)a.w;
  v[4] = (bf16_t)b.x; v[5] = (bf16_t)b.y; v[6] = (bf16_t)b.z; v[7] = (bf16_t)b.w;
  *(bf16x8*)(o + gid * 8) = v;
}

// ---------------------------------------------------------------- weight transpose + cast: w[K][N] -> wT[N][K] bf16
__global__ __launch_bounds__(256) void transpose_to_bf16(const float* __restrict__ w,
                                                         bf16_t* __restrict__ wT,
                                                         int K, int N) {
  __shared__ float t[32][33];
  int bx = blockIdx.x, by = blockIdx.y;
  int tx = threadIdx.x & 31, ty = threadIdx.x >> 5;
#pragma unroll
  for (int r = ty; r < 32; r += 8)
    t[r][tx] = w[(size_t)(by * 32 + r) * N + bx * 32 + tx];
  __syncthreads();
#pragma unroll
  for (int r = ty; r < 32; r += 8)
    wT[(size_t)(bx * 32 + r) * K + by * 32 + tx] = (bf16_t)t[tx][r];
}

// ---------------------------------------------------------------- 256x256 8-phase GEMM (non-persistent; round-12/13 proven body)
// C[M][N] = A[M][K=1024] @ Bt[N][K=1024]^T.  8 waves, BK=64, dbuf LDS 128 KiB,
// 4 phases/K-tile, counted vmcnt(8) at tile boundary only.
// T2 swizzle: k-slot' = k-slot ^ (row&7); linear gl_lds dest + pre-swizzled
// global source + swizzled ds_read (rule #21).
// TILE MAP (EPI 0): L2-residency partition (kept from r13: FETCH 192->148 MB).
// EPI 0: (a) fused pyramid L4-8 from f32 acc (16-row fragment sums + shfl
//            reduce + LDS exchange for L8) — replaces the coarsen kernel;
//        (b) L0 scatter via LDS-bounce -> 1 KB coalesced stores.
// EPI 1: fp32 C + bias.
template <int EPI>
__global__ __launch_bounds__(512, 2) void gemm256(const bf16_t* __restrict__ A,
                                                  const bf16_t* __restrict__ Bt,
                                                  float* __restrict__ Cp,
                                                  const float* __restrict__ bias,
                                                  bf16_t* __restrict__ Pq,
                                                  bf16_t* __restrict__ Pk,
                                                  bf16_t* __restrict__ Pv,
                                                  int K, int ldc, int nTilesN) {
  __shared__ __align__(16) bf16_t As[2 * 256 * 64];   // K-loop dbuf; epilogue bounce+xchg
  __shared__ __align__(16) bf16_t Bs[2 * 256 * 64];
  const int tid = threadIdx.x;
  const int w = tid >> 6, lane = tid & 63;

  int mt, ntile;
  if (EPI == 0) {
    // L2-resident map: grid 1536 = 8 XCDs x (32 M x 6 N), N-fast within XCD.
    const int x = blockIdx.x & 7;
    const int c = blockIdx.x >> 3;            // 0..191 within XCD
    mt = (x & 3) * 32 + c / 6;
    ntile = (x >> 2) * 6 + c % 6;
  } else {
    int nwg = gridDim.x;
    int chunk = nwg >> 3;
    int wgid = (blockIdx.x & 7) * chunk + (blockIdx.x >> 3);
    mt = wgid / nTilesN; ntile = wgid % nTilesN;
  }
  const int bm = mt * 256, bn = ntile * 256;

  const int wr = w >> 2, wc = w & 3;          // 2x4 wave grid; wave tile 128x64
  const int lr = lane & 15, lg = lane >> 4;
  const int sw = lr & 7;                      // T2 read-side XOR key
  const int nt = K >> 6;

  f32x4 acc[8][4] = {};

  auto stageHalf = [&](const bf16_t* __restrict__ G, int rbase, int kt, int ld,
                       bf16_t* lbuf, int h) {
#pragma unroll
    for (int j = 0; j < 2; ++j) {
      int b = j * 8 + w;
      int r3 = lane >> 3;
      int k8 = (lane & 7) ^ r3;               // T2 pre-swizzled source slot
      gl_lds16(G + (size_t)(rbase + h * 128 + b * 8 + r3) * ld + kt + k8 * 8,
               lbuf + h * 8192 + b * 512);
    }
  };

  // prologue: tiles 0 and 1 fully staged
  stageHalf(Bt, bn, 0, K, Bs, 0); stageHalf(Bt, bn, 0, K, Bs, 1);
  stageHalf(A, bm, 0, K, As, 0);  stageHalf(A, bm, 0, K, As, 1);
  if (nt > 1) {
    stageHalf(Bt, bn, 64, K, Bs + 16384, 0); stageHalf(Bt, bn, 64, K, Bs + 16384, 1);
    stageHalf(A, bm, 64, K, As + 16384, 0);  stageHalf(A, bm, 64, K, As + 16384, 1);
    asm volatile("s_waitcnt vmcnt(8)" ::: "memory");       // tile 0 landed
  } else {
    asm volatile("s_waitcnt vmcnt(0)" ::: "memory");
  }
  __syncthreads();

  for (int t = 0; t < nt; ++t) {
    const int c = t & 1;
    bf16_t* Abuf = As + c * 16384;
    bf16_t* Bbuf = Bs + c * 16384;
    const bool pf = (t + 2) < nt;
    const int kt2 = (t + 2) << 6;
    bf16x8 bfrag[4][2];

#pragma unroll
    for (int p = 0; p < 4; ++p) {
      bf16x8 afrag[2][2];
#pragma unroll
      for (int fi = 0; fi < 2; ++fi)
#pragma unroll
        for (int kk = 0; kk < 2; ++kk)
          afrag[fi][kk] = *(const bf16x8*)&Abuf[(wr * 128 + p * 32 + fi * 16 + lr) * 64 +
                                                (((kk * 4 + lg) ^ sw) * 8)];
      if (p == 0) {
#pragma unroll
        for (int fj = 0; fj < 4; ++fj)
#pragma unroll
          for (int kk = 0; kk < 2; ++kk)
            bfrag[fj][kk] = *(const bf16x8*)&Bbuf[(wc * 64 + fj * 16 + lr) * 64 +
                                                  (((kk * 4 + lg) ^ sw) * 8)];
      }
      if (pf) {
        if (p == 1) stageHalf(Bt, bn, kt2, K, Bbuf, 0);
        if (p == 2) stageHalf(Bt, bn, kt2, K, Bbuf, 1);
        if (p == 3) { stageHalf(A, bm, kt2, K, Abuf, 0); stageHalf(A, bm, kt2, K, Abuf, 1); }
      }
      __builtin_amdgcn_s_barrier();
      asm volatile("s_waitcnt lgkmcnt(0)" ::: "memory");
      __builtin_amdgcn_sched_barrier(0);
      __builtin_amdgcn_s_setprio(1);
#pragma unroll
      for (int kk = 0; kk < 2; ++kk)
#pragma unroll
        for (int fi = 0; fi < 2; ++fi)
#pragma unroll
          for (int fj = 0; fj < 4; ++fj)
            acc[p * 2 + fi][fj] = __builtin_amdgcn_mfma_f32_16x16x32_bf16(
                afrag[fi][kk], bfrag[fj][kk], acc[p * 2 + fi][fj], 0, 0, 0);
      __builtin_amdgcn_s_setprio(0);
      if (p == 3) {
        if (pf) asm volatile("s_waitcnt vmcnt(8)" ::: "memory");   // tile t+1 landed
        else    asm volatile("s_waitcnt vmcnt(0)" ::: "memory");   // tail drain
      }
      __builtin_amdgcn_s_barrier();
    }
  }

  // ---- epilogue (LDS is dead after the final barrier: non-persistent)
  if (EPI == 1) {
    float bv[4];
#pragma unroll
    for (int fj = 0; fj < 4; ++fj) bv[fj] = bias[bn + wc * 64 + fj * 16 + lr];
#pragma unroll
    for (int fi = 0; fi < 8; ++fi)
#pragma unroll
      for (int fj = 0; fj < 4; ++fj)
#pragma unroll
        for (int r = 0; r < 4; ++r) {
          int row = bm + wr * 128 + fi * 16 + lg * 4 + r;
          int col = bn + wc * 64 + fj * 16 + lr;
          Cp[(size_t)row * ldc + col] = acc[fi][fj][r] + bv[fj];
        }
  } else {
    // wave constants: band of 64 cols = one (tns, head); 256-row tile never
    // straddles the 8192-row hg boundary.
    const int tns = bn >> 10;
    const int h = ((bn & 1023) >> 6) + wc;
    const int hgRow = (bm >> 13) << 4;
    const int trow0 = (bm & 8191) + wr * 128;
    bf16_t* Pt = (tns == 0) ? Pq : (tns == 1 ? Pk : Pv);
    const float scl = (tns == 0) ? 0.125f : 1.f;
    const size_t prow = (size_t)(hgRow + h) * PROWS;

    // ---- (a) fused pyramid L4-8 from f32 acc (before any rounding).
    // 16-row group g == fragment fi: in-lane sum of 4 r's + shfl over lg.
    // q,k: mean (scl * 2^-l); v: raw sum.
    {
      const bool isv = (tns == 2);
      const int tr = bm & 8191;
      const int r4 = (tr >> 4) + wr * 8;
      const int r5 = (tr >> 5) + wr * 4;
      const int r6 = (tr >> 6) + wr * 2;
      const int r7 = (tr >> 7) + wr;
      const int r8 = (tr >> 8);
      float* xch = (float*)(As + 20480) + w * 64;   // L7 exchange: 8 waves x 64 f32
      float l7[4];
#pragma unroll
      for (int fj = 0; fj < 4; ++fj) {
        const int col = fj * 16 + lr;
        float rs[8];
#pragma unroll
        for (int g = 0; g < 8; ++g) {
          float s = acc[g][fj][0] + acc[g][fj][1] + acc[g][fj][2] + acc[g][fj][3];
          s += __shfl_xor(s, 16, 64);
          s += __shfl_xor(s, 32, 64);
          rs[g] = s;
        }
        l7[fj] = (rs[0] + rs[1] + rs[2] + rs[3]) + (rs[4] + rs[5] + rs[6] + rs[7]);
        if (lg == 0) {
          const float m4 = isv ? 1.f : scl * 0.0625f;
          const float m5 = isv ? 1.f : scl * 0.03125f;
          const float m6 = isv ? 1.f : scl * 0.015625f;
          const float m7 = isv ? 1.f : scl * 0.0078125f;
#pragma unroll
          for (int g = 0; g < 8; ++g)
            Pt[(prow + 15360 + r4 + g) * 64 + col] = (bf16_t)(rs[g] * m4);
#pragma unroll
          for (int g = 0; g < 4; ++g)
            Pt[(prow + 15872 + r5 + g) * 64 + col] =
                (bf16_t)((rs[2 * g] + rs[2 * g + 1]) * m5);
#pragma unroll
          for (int g = 0; g < 2; ++g)
            Pt[(prow + 16128 + r6 + g) * 64 + col] =
                (bf16_t)(((rs[4 * g] + rs[4 * g + 1]) + (rs[4 * g + 2] + rs[4 * g + 3])) * m6);
          Pt[(prow + 16256 + r7) * 64 + col] = (bf16_t)(l7[fj] * m7);
          xch[col] = l7[fj];
        }
      }
      __syncthreads();
      if (wr == 0 && lg == 0) {
        const float m8 = isv ? 1.f : scl * 0.00390625f;
        const float* pxch = (const float*)(As + 20480) + (w + 4) * 64;
#pragma unroll
        for (int fj = 0; fj < 4; ++fj) {
          const int col = fj * 16 + lr;
          Pt[(prow + 16320 + r8) * 64 + col] = (bf16_t)((l7[fj] + pxch[col]) * m8);
        }
      }
      __syncthreads();   // xch dead before bounce reuses As (regions disjoint, but keep ordering clean)
    }

    // ---- (b) L0 scatter via LDS bounce -> coalesced 1 KB lines
    bf16_t* lds = (w < 4) ? (As + w * 4608) : (Bs + (w - 4) * 4608);  // 64 rows x 72
    const size_t gbase = (prow + trow0) * 64;
#pragma unroll
    for (int half = 0; half < 2; ++half) {
#pragma unroll
      for (int fi4 = 0; fi4 < 4; ++fi4) {
        const int fi = half * 4 + fi4;
#pragma unroll
        for (int fj = 0; fj < 4; ++fj)
#pragma unroll
          for (int r = 0; r < 4; ++r)
            lds[(fi4 * 16 + lg * 4 + r) * 72 + fj * 16 + lr] =
                (bf16_t)(acc[fi][fj][r] * scl);
      }
      asm volatile("s_waitcnt lgkmcnt(0)" ::: "memory");   // writes visible to own wave reads
#pragma unroll
      for (int it = 0; it < 8; ++it) {
        const int row = it * 8 + (lane >> 3);
        bf16x8 v = *(const bf16x8*)&lds[row * 72 + (lane & 7) * 8];
        *(bf16x8*)(Pt + gbase + (size_t)(half * 64 + row) * 64 + (lane & 7) * 8) = v;
      }
      asm volatile("s_waitcnt lgkmcnt(0)" ::: "memory");   // reads retired before re-write
    }
  }
}

// ---------------------------------------------------------------- levels 4..8 attention (reads pyramid, y in place + Asum)
__global__ __launch_bounds__(256) void attn_hi(bf16_t* __restrict__ Pq,
                                               const bf16_t* __restrict__ Pk,
                                               const bf16_t* __restrict__ Pv,
                                               float* __restrict__ Asum) {
  const int poffA[9] = {0, 8192, 12288, 14336, 15360, 15872, 16128, 16256, 16320};
  const int tid = threadIdx.x;
  const int wv = tid >> 6, lane = tid & 63;
  const int lr = lane & 15, lg = lane >> 4;

  int bid = blockIdx.x * 4 + wv;            // 3968 problems (levels 4-8)
  int l = 4, cnt = 2048;
  while (bid >= cnt) { bid -= cnt; cnt >>= 1; ++l; }
  const int lg2nblk = 9 - l;
  const int blk = bid & ((1 << lg2nblk) - 1);
  const int hg = bid >> lg2nblk;
  const int kvblk = blk ^ 1;
  const size_t qbase = (size_t)hg * PROWS + poffA[l] + blk * 16;
  const size_t kvbase = (size_t)hg * PROWS + poffA[l] + kvblk * 16;

  f32x4 s = {};
#pragma unroll
  for (int c = 0; c < 2; ++c) {
    bf16x8 ak = *(const bf16x8*)(Pk + (kvbase + lr) * 64 + c * 32 + lg * 8);
    bf16x8 bq = *(const bf16x8*)(Pq + (qbase + lr) * 64 + c * 32 + lg * 8);
    s = __builtin_amdgcn_mfma_f32_16x16x32_bf16(ak, bq, s, 0, 0, 0);
  }
  float mx = fmaxf(fmaxf(s[0], s[1]), fmaxf(s[2], s[3]));
  mx = fmaxf(mx, __shfl_xor(mx, 16, 64));
  mx = fmaxf(mx, __shfl_xor(mx, 32, 64));
  float a[4]; float asum = 0.f;
#pragma unroll
  for (int r = 0; r < 4; ++r) { a[r] = (float)(bf16_t)__expf(s[r] - mx); asum += a[r]; }
  asum += __shfl_xor(asum, 16, 64);
  asum += __shfl_xor(asum, 32, 64);
  if (lg == 0) Asum[qbase + lr] = asum;

  const int src0 = (2 * lg) * 16 + lr;
  const int src1 = (2 * lg + 1) * 16 + lr;
  bf16x8 pa;
#pragma unroll
  for (int r = 0; r < 4; ++r) {
    float c0 = __shfl(a[r], src0, 64);
    float c1 = __shfl(a[r], src1, 64);
    pa[r]     = (lg < 2) ? (bf16_t)c0 : (bf16_t)0.f;
    pa[r + 4] = (lg < 2) ? (bf16_t)c1 : (bf16_t)0.f;
  }
#pragma unroll
  for (int dt = 0; dt < 4; ++dt) {
    bf16x8 vf;
    if (lg < 2) {
#pragma unroll
      for (int e = 0; e < 8; ++e) vf[e] = Pv[(kvbase + lg * 8 + e) * 64 + dt * 16 + lr];
    } else {
#pragma unroll
      for (int e = 0; e < 8; ++e) vf[e] = (bf16_t)0.f;
    }
    f32x4 y = __builtin_amdgcn_mfma_f32_16x16x32_bf16(pa, vf, (f32x4){}, 0, 0, 0);
#pragma unroll
    for (int r = 0; r < 4; ++r)
      Pq[(qbase + 4 * lg + r) * 64 + dt * 16 + lr] = (bf16_t)y[r];
  }
}

// ---------------------------------------------------------------- fused attn L0-3 + combine, L1-3 derived on the fly
__global__ __launch_bounds__(256) void attn_comb(const bf16_t* __restrict__ Pq,
                                                 const bf16_t* __restrict__ Pk,
                                                 const bf16_t* __restrict__ Pv,
                                                 const float* __restrict__ Ab,
                                                 bf16_t* __restrict__ attnb) {
  __shared__ __align__(16) bf16_t yl[480 * 72];   // L0@0 L1@256 L2@384 L3@448, stride 72
  __shared__ float asl[480];
  const int poffA[9] = {0, 8192, 12288, 14336, 15360, 15872, 16128, 16256, 16320};
  const int loffA[4] = {0, 256, 384, 448};
  const int hg = blockIdx.x >> 5, win = blockIdx.x & 31;
  const int tid = threadIdx.x;
  const int wv = tid >> 6, lane = tid & 63;
  const int lr = lane & 15, lg = lane >> 4;
  const size_t hb = (size_t)hg * PROWS;

  auto do_attn = [&](int l, int blkL) {
    const int blk = win * (16 >> l) + blkL;
    const int kvblk = l ? (blk ^ 1) : blk;
    const int lrow = loffA[l] + blkL * 16;
    const int q0 = (blk * 16 + lr) << l;
    const int k0 = (kvblk * 16 + lr) << l;
    const int kv0 = (kvblk * 16) << l;
    const float scl = 1.f / (float)(1 << l);

    f32x4 s = {};
#pragma unroll
    for (int c = 0; c < 2; ++c) {
      float fk[8] = {}, fq[8] = {}, t[8];
      for (int m = 0; m < (1 << l); ++m) {
        load8f(Pk + (hb + k0 + m) * 64 + c * 32 + lg * 8, t);
#pragma unroll
        for (int e = 0; e < 8; ++e) fk[e] += t[e];
        load8f(Pq + (hb + q0 + m) * 64 + c * 32 + lg * 8, t);
#pragma unroll
        for (int e = 0; e < 8; ++e) fq[e] += t[e];
      }
      bf16x8 ak, bq;
#pragma unroll
      for (int e = 0; e < 8; ++e) {
        ak[e] = (bf16_t)(fk[e] * scl);
        bq[e] = (bf16_t)(fq[e] * scl);
      }
      s = __builtin_amdgcn_mfma_f32_16x16x32_bf16(ak, bq, s, 0, 0, 0);
    }

    float mx = fmaxf(fmaxf(s[0], s[1]), fmaxf(s[2], s[3]));
    mx = fmaxf(mx, __shfl_xor(mx, 16, 64));
    mx = fmaxf(mx, __shfl_xor(mx, 32, 64));
    float a[4]; float asum = 0.f;
#pragma unroll
    for (int r = 0; r < 4; ++r) { a[r] = (float)(bf16_t)__expf(s[r] - mx); asum += a[r]; }
    asum += __shfl_xor(asum, 16, 64);
    asum += __shfl_xor(asum, 32, 64);
    if (lg == 0) asl[lrow + lr] = asum;

    if (l == 0) {
      const int src0 = (2 * lg) * 16 + lr;
      const int src1 = (2 * lg + 1) * 16 + lr;
      bf16x8 pa;
#pragma unroll
      for (int r = 0; r < 4; ++r) {
        float c0 = __shfl(a[r], src0, 64);
        float c1 = __shfl(a[r], src1, 64);
        pa[r]     = (lg < 2) ? (bf16_t)c0 : (bf16_t)0.f;
        pa[r + 4] = (lg < 2) ? (bf16_t)c1 : (bf16_t)0.f;
      }
#pragma unroll
      for (int dt = 0; dt < 4; ++dt) {
        bf16x8 vf;
        if (lg < 2) {
#pragma unroll
          for (int e = 0; e < 8; ++e) vf[e] = Pv[(hb + kv0 + lg * 8 + e) * 64 + dt * 16 + lr];
        } else {
#pragma unroll
          for (int e = 0; e < 8; ++e) vf[e] = (bf16_t)0.f;
        }
        f32x4 y = __builtin_amdgcn_mfma_f32_16x16x32_bf16(pa, vf, (f32x4){}, 0, 0, 0);
#pragma unroll
        for (int r = 0; r < 4; ++r)
          yl[(lrow + 4 * lg + r) * 72 + dt * 16 + lr] = (bf16_t)y[r];
      }
    } else {
      const int nch = 1 << (l - 1);
      bf16x8 pa[4];
      for (int ch = 0; ch < nch; ++ch) {
        if (l == 1) {
#pragma unroll
          for (int e = 0; e < 8; ++e) pa[ch][e] = (bf16_t)a[e >> 1];
        } else if (l == 2) {
          int src = (2 * ch + (lg >> 1)) * 16 + lr;
          float t0 = __shfl(a[0], src, 64), t1 = __shfl(a[1], src, 64);
          float t2 = __shfl(a[2], src, 64), t3 = __shfl(a[3], src, 64);
          float vlo = (lg & 1) ? t2 : t0;
          float vhi = (lg & 1) ? t3 : t1;
#pragma unroll
          for (int e = 0; e < 4; ++e) { pa[ch][e] = (bf16_t)vlo; pa[ch][e + 4] = (bf16_t)vhi; }
        } else {
          int src = ch * 16 + lr;
          float t0 = __shfl(a[0], src, 64), t1 = __shfl(a[1], src, 64);
          float t2 = __shfl(a[2], src, 64), t3 = __shfl(a[3], src, 64);
          float v01 = (lg & 1) ? t1 : t0;
          float v23 = (lg & 1) ? t3 : t2;
          float vv = (lg & 2) ? v23 : v01;
#pragma unroll
          for (int e = 0; e < 8; ++e) pa[ch][e] = (bf16_t)vv;
        }
      }
#pragma unroll
      for (int dt = 0; dt < 4; ++dt) {
        f32x4 y = {};
        for (int ch = 0; ch < nch; ++ch) {
          bf16x8 vf;
#pragma unroll
          for (int e = 0; e < 8; ++e)
            vf[e] = Pv[(hb + kv0 + ch * 32 + lg * 8 + e) * 64 + dt * 16 + lr];
          y = __builtin_amdgcn_mfma_f32_16x16x32_bf16(pa[ch], vf, y, 0, 0, 0);
        }
#pragma unroll
        for (int r = 0; r < 4; ++r)
          yl[(lrow + 4 * lg + r) * 72 + dt * 16 + lr] = (bf16_t)y[r];
      }
    }
  };

  do_attn(0, wv * 4 + 0); do_attn(0, wv * 4 + 1);
  do_attn(0, wv * 4 + 2); do_attn(0, wv * 4 + 3);
  do_attn(1, wv * 2 + 0); do_attn(1, wv * 2 + 1);
  do_attn(2, wv);
  if (wv < 2) do_attn(3, wv);
  __syncthreads();

  const int d8 = tid & 7, rg = tid >> 3;
#pragma unroll
  for (int i = 0; i < 8; ++i) {
    const int r = rg * 8 + i;
    const int t = win * 256 + r;
    float acc[8] = {};
    float asum = 0.f;
#pragma unroll
    for (int l = 0; l < 4; ++l) {
      const int row = loffA[l] + (r >> l);
      asum += asl[row];
      bf16x8 v = *(const bf16x8*)&yl[row * 72 + d8 * 8];
#pragma unroll
      for (int e = 0; e < 8; ++e) acc[e] += (float)v[e];
    }
#pragma unroll
    for (int l = 4; l < 9; ++l) {
      const size_t grow = hb + poffA[l] + (t >> l);
      asum += Ab[grow];
      bf16x8 v = *(const bf16x8*)(Pq + grow * 64 + d8 * 8);
#pragma unroll
      for (int e = 0; e < 8; ++e) acc[e] += (float)v[e];
    }
    const float inv = 1.f / (asum + 1e-8f);
    bf16x8 o;
#pragma unroll
    for (int e = 0; e < 8; ++e) o[e] = (bf16_t)(acc[e] * inv);
    *(bf16x8*)(attnb + ((size_t)(hg >> 4) * 8192 + t) * 1024 + (hg & 15) * 64 + d8 * 8) = o;
  }
}

// ---------------------------------------------------------------- launch
// Workspace (bytes), total 481,550,336 (~459.2 MiB):
//   Pq @ 0           127.75 MiB  [64][16352][64] bf16 (q; L4-8 y in place)
//   Pk @ 133955584   127.75 MiB
//   Pv @ 267911168   127.75 MiB
//   Ab @ 401866752   4 MiB       [64][16352] f32 Asum (L4-8 used)
//   woutT @ 406052864  2 MiB
//   x_bf @ 408150016  64 MiB     (dead after gemm1)
//   wqkvT @ 475258880 6 MiB      (dead after gemm1)
// Alias: attnb @ 408150016 over x_bf (dead after gemm1).
extern "C" void kernel_launch(void* const* d_in, const int* in_sizes, int n_in,
                              void* d_out, int out_size, void* d_ws, size_t ws_size,
                              hipStream_t stream) {
  const float* x = (const float*)d_in[0];
  const float* wqkv = (const float*)d_in[1];
  const float* wout = (const float*)d_in[2];
  const float* bout = (const float*)d_in[3];
  float* out = (float*)d_out;
  (void)in_sizes; (void)n_in; (void)out_size; (void)ws_size;

  char* base = (char*)d_ws;
  bf16_t* Pq    = (bf16_t*)(base + 0);
  bf16_t* Pk    = (bf16_t*)(base + 133955584);
  bf16_t* Pv    = (bf16_t*)(base + 267911168);
  float*  Ab    = (float*)(base + 401866752);
  bf16_t* woutT = (bf16_t*)(base + 406052864);
  bf16_t* x_bf  = (bf16_t*)(base + 408150016);
  bf16_t* wqkvT = (bf16_t*)(base + 475258880);
  bf16_t* attnb = (bf16_t*)(base + 408150016);   // alias over dead x_bf

  cvt_f32_to_bf16<<<16384, 256, 0, stream>>>(x, x_bf);
  transpose_to_bf16<<<dim3(96, 32), 256, 0, stream>>>(wqkv, wqkvT, 1024, 3072);
  transpose_to_bf16<<<dim3(32, 32), 256, 0, stream>>>(wout, woutT, 1024, 1024);

  // qkv GEMM: coalesced L0 scatter + fused pyramid L4-8 (coarsen kernel eliminated)
  gemm256<0><<<1536, 512, 0, stream>>>(x_bf, wqkvT, nullptr, nullptr, Pq, Pk, Pv,
                                       1024, 3072, 12);

  attn_hi<<<992, 256, 0, stream>>>(Pq, Pk, Pv, Ab);
  attn_comb<<<2048, 256, 0, stream>>>(Pq, Pk, Pv, Ab, attnb);

  // output GEMM (non-persistent), fp32 + bias
  gemm256<1><<<512, 512, 0, stream>>>(attnb, woutT, out, bout, nullptr, nullptr, nullptr,
                                      1024, 1024, 4);
}

// Round 15
// 510.536 us; speedup vs baseline: 1.1899x; 1.0070x over previous
//
#include <hip/hip_runtime.h>
#include <hip/hip_bf16.h>

typedef __bf16 bf16_t;
typedef bf16_t bf16x8 __attribute__((ext_vector_type(8)));
typedef float f32x4 __attribute__((ext_vector_type(4)));

// Pyramid layout: P[hg][16352][64] bf16, hg = b*16+h (64 head-groups).
// Row offsets per level l: {0,8192,12288,14336,15360,15872,16128,16256,16320}.
// Levels 1-3 are NEVER materialized (derived on the fly in attn_comb).
// Levels 4-8 are built in gemm1's epilogue from f32 accumulators.
#define PROWS 16352

// ---------------------------------------------------------------- helpers
__device__ __forceinline__ void gl_lds16(const bf16_t* g, bf16_t* l) {
  __builtin_amdgcn_global_load_lds(
      (const __attribute__((address_space(1))) void*)g,
      (__attribute__((address_space(3))) void*)l,
      16, 0, 0);
}

__device__ __forceinline__ void load8f(const bf16_t* p, float* f) {
  bf16x8 v = *(const bf16x8*)p;
#pragma unroll
  for (int e = 0; e < 8; ++e) f[e] = (float)v[e];
}

// ---------------------------------------------------------------- fused prep: x cvt + both weight transposes (one dispatch)
// blocks [0,16384): cvt x f32->bf16 (8 elems/thread)
// blocks [16384,19456): wqkv[1024][3072] -> wqkvT[3072][1024] bf16
// blocks [19456,20480): wout[1024][1024] -> woutT[1024][1024] bf16
__global__ __launch_bounds__(256) void prep(const float* __restrict__ x,
                                            bf16_t* __restrict__ x_bf,
                                            const float* __restrict__ wqkv,
                                            bf16_t* __restrict__ wqkvT,
                                            const float* __restrict__ wout,
                                            bf16_t* __restrict__ woutT) {
  __shared__ float t[32][33];
  const int bid = blockIdx.x;
  if (bid < 16384) {
    size_t gid = (size_t)bid * 256 + threadIdx.x;
    const float4* p = (const float4*)x + gid * 2;
    float4 a = p[0], b = p[1];
    bf16x8 v;
    v[0] = (bf16_t)a.x; v[1] = (bf16_t)a.y; v[2] = (bf16_t)a.z; v[3] = (bf16_t)a.w;
    v[4] = (bf16_t)b.x; v[5] = (bf16_t)b.y; v[6] = (bf16_t)b.z; v[7] = (bf16_t)b.w;
    *(bf16x8*)(x_bf + gid * 8) = v;
    return;
  }
  const float* w;
  bf16_t* wT;
  int bx, by, N;
  if (bid < 19456) {
    int r = bid - 16384;                 // 3072 blocks: 96 x 32
    bx = r % 96; by = r / 96; N = 3072;
    w = wqkv; wT = wqkvT;
  } else {
    int r = bid - 19456;                 // 1024 blocks: 32 x 32
    bx = r & 31; by = r >> 5; N = 1024;
    w = wout; wT = woutT;
  }
  const int K = 1024;
  int tx = threadIdx.x & 31, ty = threadIdx.x >> 5;
#pragma unroll
  for (int r = ty; r < 32; r += 8)
    t[r][tx] = w[(size_t)(by * 32 + r) * N + bx * 32 + tx];
  __syncthreads();
#pragma unroll
  for (int r = ty; r < 32; r += 8)
    wT[(size_t)(bx * 32 + r) * K + by * 32 + tx] = (bf16_t)t[tx][r];
}

// ---------------------------------------------------------------- 256x256 8-phase GEMM (non-persistent; round-12/13 proven body)
// C[M][N] = A[M][K=1024] @ Bt[N][K=1024]^T.  8 waves, BK=64, dbuf LDS 128 KiB,
// 4 phases/K-tile, counted vmcnt(8) at tile boundary only.
// T2 swizzle: k-slot' = k-slot ^ (row&7); linear gl_lds dest + pre-swizzled
// global source + swizzled ds_read (rule #21).
// TILE MAP (EPI 0): L2-residency partition (FETCH 192->148 MB, r13).
// EPI 0: (a) fused pyramid L4-8 from f32 acc; (b) L0 scatter via LDS-bounce.
// EPI 1: fp32 C + bias.
template <int EPI>
__global__ __launch_bounds__(512, 2) void gemm256(const bf16_t* __restrict__ A,
                                                  const bf16_t* __restrict__ Bt,
                                                  float* __restrict__ Cp,
                                                  const float* __restrict__ bias,
                                                  bf16_t* __restrict__ Pq,
                                                  bf16_t* __restrict__ Pk,
                                                  bf16_t* __restrict__ Pv,
                                                  int K, int ldc, int nTilesN) {
  __shared__ __align__(16) bf16_t As[2 * 256 * 64];   // K-loop dbuf; epilogue bounce+xchg
  __shared__ __align__(16) bf16_t Bs[2 * 256 * 64];
  const int tid = threadIdx.x;
  const int w = tid >> 6, lane = tid & 63;

  int mt, ntile;
  if (EPI == 0) {
    // L2-resident map: grid 1536 = 8 XCDs x (32 M x 6 N), N-fast within XCD.
    const int x = blockIdx.x & 7;
    const int c = blockIdx.x >> 3;            // 0..191 within XCD
    mt = (x & 3) * 32 + c / 6;
    ntile = (x >> 2) * 6 + c % 6;
  } else {
    int nwg = gridDim.x;
    int chunk = nwg >> 3;
    int wgid = (blockIdx.x & 7) * chunk + (blockIdx.x >> 3);
    mt = wgid / nTilesN; ntile = wgid % nTilesN;
  }
  const int bm = mt * 256, bn = ntile * 256;

  const int wr = w >> 2, wc = w & 3;          // 2x4 wave grid; wave tile 128x64
  const int lr = lane & 15, lg = lane >> 4;
  const int sw = lr & 7;                      // T2 read-side XOR key
  const int nt = K >> 6;

  f32x4 acc[8][4] = {};

  auto stageHalf = [&](const bf16_t* __restrict__ G, int rbase, int kt, int ld,
                       bf16_t* lbuf, int h) {
#pragma unroll
    for (int j = 0; j < 2; ++j) {
      int b = j * 8 + w;
      int r3 = lane >> 3;
      int k8 = (lane & 7) ^ r3;               // T2 pre-swizzled source slot
      gl_lds16(G + (size_t)(rbase + h * 128 + b * 8 + r3) * ld + kt + k8 * 8,
               lbuf + h * 8192 + b * 512);
    }
  };

  // prologue: tiles 0 and 1 fully staged
  stageHalf(Bt, bn, 0, K, Bs, 0); stageHalf(Bt, bn, 0, K, Bs, 1);
  stageHalf(A, bm, 0, K, As, 0);  stageHalf(A, bm, 0, K, As, 1);
  if (nt > 1) {
    stageHalf(Bt, bn, 64, K, Bs + 16384, 0); stageHalf(Bt, bn, 64, K, Bs + 16384, 1);
    stageHalf(A, bm, 64, K, As + 16384, 0);  stageHalf(A, bm, 64, K, As + 16384, 1);
    asm volatile("s_waitcnt vmcnt(8)" ::: "memory");       // tile 0 landed
  } else {
    asm volatile("s_waitcnt vmcnt(0)" ::: "memory");
  }
  __syncthreads();

  for (int t = 0; t < nt; ++t) {
    const int c = t & 1;
    bf16_t* Abuf = As + c * 16384;
    bf16_t* Bbuf = Bs + c * 16384;
    const bool pf = (t + 2) < nt;
    const int kt2 = (t + 2) << 6;
    bf16x8 bfrag[4][2];

#pragma unroll
    for (int p = 0; p < 4; ++p) {
      bf16x8 afrag[2][2];
#pragma unroll
      for (int fi = 0; fi < 2; ++fi)
#pragma unroll
        for (int kk = 0; kk < 2; ++kk)
          afrag[fi][kk] = *(const bf16x8*)&Abuf[(wr * 128 + p * 32 + fi * 16 + lr) * 64 +
                                                (((kk * 4 + lg) ^ sw) * 8)];
      if (p == 0) {
#pragma unroll
        for (int fj = 0; fj < 4; ++fj)
#pragma unroll
          for (int kk = 0; kk < 2; ++kk)
            bfrag[fj][kk] = *(const bf16x8*)&Bbuf[(wc * 64 + fj * 16 + lr) * 64 +
                                                  (((kk * 4 + lg) ^ sw) * 8)];
      }
      if (pf) {
        if (p == 1) stageHalf(Bt, bn, kt2, K, Bbuf, 0);
        if (p == 2) stageHalf(Bt, bn, kt2, K, Bbuf, 1);
        if (p == 3) { stageHalf(A, bm, kt2, K, Abuf, 0); stageHalf(A, bm, kt2, K, Abuf, 1); }
      }
      __builtin_amdgcn_s_barrier();
      asm volatile("s_waitcnt lgkmcnt(0)" ::: "memory");
      __builtin_amdgcn_sched_barrier(0);
      __builtin_amdgcn_s_setprio(1);
#pragma unroll
      for (int kk = 0; kk < 2; ++kk)
#pragma unroll
        for (int fi = 0; fi < 2; ++fi)
#pragma unroll
          for (int fj = 0; fj < 4; ++fj)
            acc[p * 2 + fi][fj] = __builtin_amdgcn_mfma_f32_16x16x32_bf16(
                afrag[fi][kk], bfrag[fj][kk], acc[p * 2 + fi][fj], 0, 0, 0);
      __builtin_amdgcn_s_setprio(0);
      if (p == 3) {
        if (pf) asm volatile("s_waitcnt vmcnt(8)" ::: "memory");   // tile t+1 landed
        else    asm volatile("s_waitcnt vmcnt(0)" ::: "memory");   // tail drain
      }
      __builtin_amdgcn_s_barrier();
    }
  }

  // ---- epilogue (LDS is dead after the final barrier: non-persistent)
  if (EPI == 1) {
    float bv[4];
#pragma unroll
    for (int fj = 0; fj < 4; ++fj) bv[fj] = bias[bn + wc * 64 + fj * 16 + lr];
#pragma unroll
    for (int fi = 0; fi < 8; ++fi)
#pragma unroll
      for (int fj = 0; fj < 4; ++fj)
#pragma unroll
        for (int r = 0; r < 4; ++r) {
          int row = bm + wr * 128 + fi * 16 + lg * 4 + r;
          int col = bn + wc * 64 + fj * 16 + lr;
          Cp[(size_t)row * ldc + col] = acc[fi][fj][r] + bv[fj];
        }
  } else {
    // wave constants: band of 64 cols = one (tns, head); 256-row tile never
    // straddles the 8192-row hg boundary.
    const int tns = bn >> 10;
    const int h = ((bn & 1023) >> 6) + wc;
    const int hgRow = (bm >> 13) << 4;
    const int trow0 = (bm & 8191) + wr * 128;
    bf16_t* Pt = (tns == 0) ? Pq : (tns == 1 ? Pk : Pv);
    const float scl = (tns == 0) ? 0.125f : 1.f;
    const size_t prow = (size_t)(hgRow + h) * PROWS;

    // ---- (a) fused pyramid L4-8 from f32 acc (before any rounding).
    {
      const bool isv = (tns == 2);
      const int tr = bm & 8191;
      const int r4 = (tr >> 4) + wr * 8;
      const int r5 = (tr >> 5) + wr * 4;
      const int r6 = (tr >> 6) + wr * 2;
      const int r7 = (tr >> 7) + wr;
      const int r8 = (tr >> 8);
      float* xch = (float*)(As + 20480) + w * 64;   // L7 exchange: 8 waves x 64 f32
      float l7[4];
#pragma unroll
      for (int fj = 0; fj < 4; ++fj) {
        const int col = fj * 16 + lr;
        float rs[8];
#pragma unroll
        for (int g = 0; g < 8; ++g) {
          float s = acc[g][fj][0] + acc[g][fj][1] + acc[g][fj][2] + acc[g][fj][3];
          s += __shfl_xor(s, 16, 64);
          s += __shfl_xor(s, 32, 64);
          rs[g] = s;
        }
        l7[fj] = (rs[0] + rs[1] + rs[2] + rs[3]) + (rs[4] + rs[5] + rs[6] + rs[7]);
        if (lg == 0) {
          const float m4 = isv ? 1.f : scl * 0.0625f;
          const float m5 = isv ? 1.f : scl * 0.03125f;
          const float m6 = isv ? 1.f : scl * 0.015625f;
          const float m7 = isv ? 1.f : scl * 0.0078125f;
#pragma unroll
          for (int g = 0; g < 8; ++g)
            Pt[(prow + 15360 + r4 + g) * 64 + col] = (bf16_t)(rs[g] * m4);
#pragma unroll
          for (int g = 0; g < 4; ++g)
            Pt[(prow + 15872 + r5 + g) * 64 + col] =
                (bf16_t)((rs[2 * g] + rs[2 * g + 1]) * m5);
#pragma unroll
          for (int g = 0; g < 2; ++g)
            Pt[(prow + 16128 + r6 + g) * 64 + col] =
                (bf16_t)(((rs[4 * g] + rs[4 * g + 1]) + (rs[4 * g + 2] + rs[4 * g + 3])) * m6);
          Pt[(prow + 16256 + r7) * 64 + col] = (bf16_t)(l7[fj] * m7);
          xch[col] = l7[fj];
        }
      }
      __syncthreads();
      if (wr == 0 && lg == 0) {
        const float m8 = isv ? 1.f : scl * 0.00390625f;
        const float* pxch = (const float*)(As + 20480) + (w + 4) * 64;
#pragma unroll
        for (int fj = 0; fj < 4; ++fj) {
          const int col = fj * 16 + lr;
          Pt[(prow + 16320 + r8) * 64 + col] = (bf16_t)((l7[fj] + pxch[col]) * m8);
        }
      }
      // no second sync needed: bounce region (bytes 0..36863 of As/Bs) is
      // disjoint from xch (As bytes 40960+), and all xch reads happened above.
    }

    // ---- (b) L0 scatter via LDS bounce -> coalesced 1 KB lines
    bf16_t* lds = (w < 4) ? (As + w * 4608) : (Bs + (w - 4) * 4608);  // 64 rows x 72
    const size_t gbase = (prow + trow0) * 64;
#pragma unroll
    for (int half = 0; half < 2; ++half) {
#pragma unroll
      for (int fi4 = 0; fi4 < 4; ++fi4) {
        const int fi = half * 4 + fi4;
#pragma unroll
        for (int fj = 0; fj < 4; ++fj)
#pragma unroll
          for (int r = 0; r < 4; ++r)
            lds[(fi4 * 16 + lg * 4 + r) * 72 + fj * 16 + lr] =
                (bf16_t)(acc[fi][fj][r] * scl);
      }
      asm volatile("s_waitcnt lgkmcnt(0)" ::: "memory");   // writes visible to own wave reads
#pragma unroll
      for (int it = 0; it < 8; ++it) {
        const int row = it * 8 + (lane >> 3);
        bf16x8 v = *(const bf16x8*)&lds[row * 72 + (lane & 7) * 8];
        *(bf16x8*)(Pt + gbase + (size_t)(half * 64 + row) * 64 + (lane & 7) * 8) = v;
      }
      asm volatile("s_waitcnt lgkmcnt(0)" ::: "memory");   // reads retired before re-write
    }
  }
}

// ---------------------------------------------------------------- levels 4..8 attention (reads pyramid, y in place + Asum)
__global__ __launch_bounds__(256) void attn_hi(bf16_t* __restrict__ Pq,
                                               const bf16_t* __restrict__ Pk,
                                               const bf16_t* __restrict__ Pv,
                                               float* __restrict__ Asum) {
  const int poffA[9] = {0, 8192, 12288, 14336, 15360, 15872, 16128, 16256, 16320};
  const int tid = threadIdx.x;
  const int wv = tid >> 6, lane = tid & 63;
  const int lr = lane & 15, lg = lane >> 4;

  int bid = blockIdx.x * 4 + wv;            // 3968 problems (levels 4-8)
  int l = 4, cnt = 2048;
  while (bid >= cnt) { bid -= cnt; cnt >>= 1; ++l; }
  const int lg2nblk = 9 - l;
  const int blk = bid & ((1 << lg2nblk) - 1);
  const int hg = bid >> lg2nblk;
  const int kvblk = blk ^ 1;
  const size_t qbase = (size_t)hg * PROWS + poffA[l] + blk * 16;
  const size_t kvbase = (size_t)hg * PROWS + poffA[l] + kvblk * 16;

  f32x4 s = {};
#pragma unroll
  for (int c = 0; c < 2; ++c) {
    bf16x8 ak = *(const bf16x8*)(Pk + (kvbase + lr) * 64 + c * 32 + lg * 8);
    bf16x8 bq = *(const bf16x8*)(Pq + (qbase + lr) * 64 + c * 32 + lg * 8);
    s = __builtin_amdgcn_mfma_f32_16x16x32_bf16(ak, bq, s, 0, 0, 0);
  }
  float mx = fmaxf(fmaxf(s[0], s[1]), fmaxf(s[2], s[3]));
  mx = fmaxf(mx, __shfl_xor(mx, 16, 64));
  mx = fmaxf(mx, __shfl_xor(mx, 32, 64));
  float a[4]; float asum = 0.f;
#pragma unroll
  for (int r = 0; r < 4; ++r) { a[r] = (float)(bf16_t)__expf(s[r] - mx); asum += a[r]; }
  asum += __shfl_xor(asum, 16, 64);
  asum += __shfl_xor(asum, 32, 64);
  if (lg == 0) Asum[qbase + lr] = asum;

  const int src0 = (2 * lg) * 16 + lr;
  const int src1 = (2 * lg + 1) * 16 + lr;
  bf16x8 pa;
#pragma unroll
  for (int r = 0; r < 4; ++r) {
    float c0 = __shfl(a[r], src0, 64);
    float c1 = __shfl(a[r], src1, 64);
    pa[r]     = (lg < 2) ? (bf16_t)c0 : (bf16_t)0.f;
    pa[r + 4] = (lg < 2) ? (bf16_t)c1 : (bf16_t)0.f;
  }
#pragma unroll
  for (int dt = 0; dt < 4; ++dt) {
    bf16x8 vf;
    if (lg < 2) {
#pragma unroll
      for (int e = 0; e < 8; ++e) vf[e] = Pv[(kvbase + lg * 8 + e) * 64 + dt * 16 + lr];
    } else {
#pragma unroll
      for (int e = 0; e < 8; ++e) vf[e] = (bf16_t)0.f;
    }
    f32x4 y = __builtin_amdgcn_mfma_f32_16x16x32_bf16(pa, vf, (f32x4){}, 0, 0, 0);
#pragma unroll
    for (int r = 0; r < 4; ++r)
      Pq[(qbase + 4 * lg + r) * 64 + dt * 16 + lr] = (bf16_t)y[r];
  }
}

// ---------------------------------------------------------------- fused attn L0-3 + combine, L1-3 derived on the fly
__global__ __launch_bounds__(256) void attn_comb(const bf16_t* __restrict__ Pq,
                                                 const bf16_t* __restrict__ Pk,
                                                 const bf16_t* __restrict__ Pv,
                                                 const float* __restrict__ Ab,
                                                 bf16_t* __restrict__ attnb) {
  __shared__ __align__(16) bf16_t yl[480 * 72];   // L0@0 L1@256 L2@384 L3@448, stride 72
  __shared__ float asl[480];
  const int poffA[9] = {0, 8192, 12288, 14336, 15360, 15872, 16128, 16256, 16320};
  const int loffA[4] = {0, 256, 384, 448};
  const int hg = blockIdx.x >> 5, win = blockIdx.x & 31;
  const int tid = threadIdx.x;
  const int wv = tid >> 6, lane = tid & 63;
  const int lr = lane & 15, lg = lane >> 4;
  const size_t hb = (size_t)hg * PROWS;

  auto do_attn = [&](int l, int blkL) {
    const int blk = win * (16 >> l) + blkL;
    const int kvblk = l ? (blk ^ 1) : blk;
    const int lrow = loffA[l] + blkL * 16;
    const int q0 = (blk * 16 + lr) << l;
    const int k0 = (kvblk * 16 + lr) << l;
    const int kv0 = (kvblk * 16) << l;
    const float scl = 1.f / (float)(1 << l);

    f32x4 s = {};
#pragma unroll
    for (int c = 0; c < 2; ++c) {
      float fk[8] = {}, fq[8] = {}, t[8];
      for (int m = 0; m < (1 << l); ++m) {
        load8f(Pk + (hb + k0 + m) * 64 + c * 32 + lg * 8, t);
#pragma unroll
        for (int e = 0; e < 8; ++e) fk[e] += t[e];
        load8f(Pq + (hb + q0 + m) * 64 + c * 32 + lg * 8, t);
#pragma unroll
        for (int e = 0; e < 8; ++e) fq[e] += t[e];
      }
      bf16x8 ak, bq;
#pragma unroll
      for (int e = 0; e < 8; ++e) {
        ak[e] = (bf16_t)(fk[e] * scl);
        bq[e] = (bf16_t)(fq[e] * scl);
      }
      s = __builtin_amdgcn_mfma_f32_16x16x32_bf16(ak, bq, s, 0, 0, 0);
    }

    float mx = fmaxf(fmaxf(s[0], s[1]), fmaxf(s[2], s[3]));
    mx = fmaxf(mx, __shfl_xor(mx, 16, 64));
    mx = fmaxf(mx, __shfl_xor(mx, 32, 64));
    float a[4]; float asum = 0.f;
#pragma unroll
    for (int r = 0; r < 4; ++r) { a[r] = (float)(bf16_t)__expf(s[r] - mx); asum += a[r]; }
    asum += __shfl_xor(asum, 16, 64);
    asum += __shfl_xor(asum, 32, 64);
    if (lg == 0) asl[lrow + lr] = asum;

    if (l == 0) {
      const int src0 = (2 * lg) * 16 + lr;
      const int src1 = (2 * lg + 1) * 16 + lr;
      bf16x8 pa;
#pragma unroll
      for (int r = 0; r < 4; ++r) {
        float c0 = __shfl(a[r], src0, 64);
        float c1 = __shfl(a[r], src1, 64);
        pa[r]     = (lg < 2) ? (bf16_t)c0 : (bf16_t)0.f;
        pa[r + 4] = (lg < 2) ? (bf16_t)c1 : (bf16_t)0.f;
      }
#pragma unroll
      for (int dt = 0; dt < 4; ++dt) {
        bf16x8 vf;
        if (lg < 2) {
#pragma unroll
          for (int e = 0; e < 8; ++e) vf[e] = Pv[(hb + kv0 + lg * 8 + e) * 64 + dt * 16 + lr];
        } else {
#pragma unroll
          for (int e = 0; e < 8; ++e) vf[e] = (bf16_t)0.f;
        }
        f32x4 y = __builtin_amdgcn_mfma_f32_16x16x32_bf16(pa, vf, (f32x4){}, 0, 0, 0);
#pragma unroll
        for (int r = 0; r < 4; ++r)
          yl[(lrow + 4 * lg + r) * 72 + dt * 16 + lr] = (bf16_t)y[r];
      }
    } else {
      const int nch = 1 << (l - 1);
      bf16x8 pa[4];
      for (int ch = 0; ch < nch; ++ch) {
        if (l == 1) {
#pragma unroll
          for (int e = 0; e < 8; ++e) pa[ch][e] = (bf16_t)a[e >> 1];
        } else if (l == 2) {
          int src = (2 * ch + (lg >> 1)) * 16 + lr;
          float t0 = __shfl(a[0], src, 64), t1 = __shfl(a[1], src, 64);
          float t2 = __shfl(a[2], src, 64), t3 = __shfl(a[3], src, 64);
          float vlo = (lg & 1) ? t2 : t0;
          float vhi = (lg & 1) ? t3 : t1;
#pragma unroll
          for (int e = 0; e < 4; ++e) { pa[ch][e] = (bf16_t)vlo; pa[ch][e + 4] = (bf16_t)vhi; }
        } else {
          int src = ch * 16 + lr;
          float t0 = __shfl(a[0], src, 64), t1 = __shfl(a[1], src, 64);
          float t2 = __shfl(a[2], src, 64), t3 = __shfl(a[3], src, 64);
          float v01 = (lg & 1) ? t1 : t0;
          float v23 = (lg & 1) ? t3 : t2;
          float vv = (lg & 2) ? v23 : v01;
#pragma unroll
          for (int e = 0; e < 8; ++e) pa[ch][e] = (bf16_t)vv;
        }
      }
#pragma unroll
      for (int dt = 0; dt < 4; ++dt) {
        f32x4 y = {};
        for (int ch = 0; ch < nch; ++ch) {
          bf16x8 vf;
#pragma unroll
          for (int e = 0; e < 8; ++e)
            vf[e] = Pv[(hb + kv0 + ch * 32 + lg * 8 + e) * 64 + dt * 16 + lr];
          y = __builtin_amdgcn_mfma_f32_16x16x32_bf16(pa[ch], vf, y, 0, 0, 0);
        }
#pragma unroll
        for (int r = 0; r < 4; ++r)
          yl[(lrow + 4 * lg + r) * 72 + dt * 16 + lr] = (bf16_t)y[r];
      }
    }
  };

  do_attn(0, wv * 4 + 0); do_attn(0, wv * 4 + 1);
  do_attn(0, wv * 4 + 2); do_attn(0, wv * 4 + 3);
  do_attn(1, wv * 2 + 0); do_attn(1, wv * 2 + 1);
  do_attn(2, wv);
  if (wv < 2) do_attn(3, wv);
  __syncthreads();

  const int d8 = tid & 7, rg = tid >> 3;
#pragma unroll
  for (int i = 0; i < 8; ++i) {
    const int r = rg * 8 + i;
    const int t = win * 256 + r;
    float acc[8] = {};
    float asum = 0.f;
#pragma unroll
    for (int l = 0; l < 4; ++l) {
      const int row = loffA[l] + (r >> l);
      asum += asl[row];
      bf16x8 v = *(const bf16x8*)&yl[row * 72 + d8 * 8];
#pragma unroll
      for (int e = 0; e < 8; ++e) acc[e] += (float)v[e];
    }
#pragma unroll
    for (int l = 4; l < 9; ++l) {
      const size_t grow = hb + poffA[l] + (t >> l);
      asum += Ab[grow];
      bf16x8 v = *(const bf16x8*)(Pq + grow * 64 + d8 * 8);
#pragma unroll
      for (int e = 0; e < 8; ++e) acc[e] += (float)v[e];
    }
    const float inv = 1.f / (asum + 1e-8f);
    bf16x8 o;
#pragma unroll
    for (int e = 0; e < 8; ++e) o[e] = (bf16_t)(acc[e] * inv);
    *(bf16x8*)(attnb + ((size_t)(hg >> 4) * 8192 + t) * 1024 + (hg & 15) * 64 + d8 * 8) = o;
  }
}

// ---------------------------------------------------------------- launch
// Workspace (bytes), total 481,550,336 (~459.2 MiB):
//   Pq @ 0           127.75 MiB  [64][16352][64] bf16 (q; L4-8 y in place)
//   Pk @ 133955584   127.75 MiB
//   Pv @ 267911168   127.75 MiB
//   Ab @ 401866752   4 MiB       [64][16352] f32 Asum (L4-8 used)
//   woutT @ 406052864  2 MiB
//   x_bf @ 408150016  64 MiB     (dead after gemm1)
//   wqkvT @ 475258880 6 MiB      (dead after gemm1)
// Alias: attnb @ 408150016 over x_bf (dead after gemm1).
extern "C" void kernel_launch(void* const* d_in, const int* in_sizes, int n_in,
                              void* d_out, int out_size, void* d_ws, size_t ws_size,
                              hipStream_t stream) {
  const float* x = (const float*)d_in[0];
  const float* wqkv = (const float*)d_in[1];
  const float* wout = (const float*)d_in[2];
  const float* bout = (const float*)d_in[3];
  float* out = (float*)d_out;
  (void)in_sizes; (void)n_in; (void)out_size; (void)ws_size;

  char* base = (char*)d_ws;
  bf16_t* Pq    = (bf16_t*)(base + 0);
  bf16_t* Pk    = (bf16_t*)(base + 133955584);
  bf16_t* Pv    = (bf16_t*)(base + 267911168);
  float*  Ab    = (float*)(base + 401866752);
  bf16_t* woutT = (bf16_t*)(base + 406052864);
  bf16_t* x_bf  = (bf16_t*)(base + 408150016);
  bf16_t* wqkvT = (bf16_t*)(base + 475258880);
  bf16_t* attnb = (bf16_t*)(base + 408150016);   // alias over dead x_bf

  // fused prep: cvt + both weight transposes (one dispatch)
  prep<<<20480, 256, 0, stream>>>(x, x_bf, wqkv, wqkvT, wout, woutT);

  // qkv GEMM: coalesced L0 scatter + fused pyramid L4-8
  gemm256<0><<<1536, 512, 0, stream>>>(x_bf, wqkvT, nullptr, nullptr, Pq, Pk, Pv,
                                       1024, 3072, 12);

  attn_hi<<<992, 256, 0, stream>>>(Pq, Pk, Pv, Ab);
  attn_comb<<<2048, 256, 0, stream>>>(Pq, Pk, Pv, Ab, attnb);

  // output GEMM (non-persistent), fp32 + bias
  gemm256<1><<<512, 512, 0, stream>>>(attnb, woutT, out, bout, nullptr, nullptr, nullptr,
                                      1024, 1024, 4);
}